// Round 17
// baseline (122.544 us; speedup 1.0000x reference)
//
#include <hip/hip_runtime.h>
#include <hip/hip_bf16.h>

#define CI_ 64
#define CO_ 128
#define NPIX 4096
#define CQ_ 16
#define EPS_ 1e-5f

typedef __attribute__((ext_vector_type(8))) __bf16 bf16x8;
typedef __attribute__((ext_vector_type(4))) __bf16 bf16x4;
typedef __attribute__((ext_vector_type(4))) float f32x4;

// transpose x -> xT[b][n][ci] bf16
__global__ __launch_bounds__(256) void z_prepx(
    const float* __restrict__ x, __bf16* __restrict__ xT)
{
    __shared__ float tl[64][65];
    int b = blockIdx.x >> 6;
    int n0 = (blockIdx.x & 63) * 64;
    int tid = threadIdx.x;
    int nn = tid & 63, c4 = tid >> 6;
#pragma unroll
    for (int p = 0; p < 16; ++p) {
        int ci = p * 4 + c4;
        tl[ci][nn] = x[((size_t)b * CI_ + ci) * NPIX + n0 + nn];
    }
    __syncthreads();
#pragma unroll
    for (int p = 0; p < 2; ++p) {
        int idx = p * 256 + tid;
        int n = idx >> 3, cig = idx & 7;
        bf16x8 vv;
#pragma unroll
        for (int j = 0; j < 8; ++j) vv[j] = (__bf16)tl[cig * 8 + j][n];
        ((bf16x8*)xT)[((size_t)b * NPIX + n0 + n) * 8 + cig] = vv;
    }
}

// W3 -> Wt2[co][tap*64+ci] bf16
__global__ __launch_bounds__(256) void z_prepw(
    const float* __restrict__ W3, __bf16* __restrict__ Wt2)
{
    int o = blockIdx.x * 256 + threadIdx.x;
    int co = o / 576;
    int r = o - co * 576;
    int tap = r >> 6;
    int ci = r & 63;
    Wt2[o] = (__bf16)W3[((size_t)co * CI_ + ci) * 9 + tap];
}

// Wg|Wf|Wr|Wa|Wq|Wk|Wv -> bf16 concatenated (118784 elems)
__global__ __launch_bounds__(256) void z_prepfw2(
    const float* __restrict__ Wg, const float* __restrict__ Wf, const float* __restrict__ Wr,
    const float* __restrict__ Wa, const float* __restrict__ Wq, const float* __restrict__ Wk,
    const float* __restrict__ Wv, __bf16* __restrict__ Wb)
{
    int i = blockIdx.x * 256 + threadIdx.x;
    if (i >= 118784) return;
    float val;
    if (i < 32768) val = Wg[i];
    else if (i < 81920) val = Wf[i - 32768];
    else if (i < 90112) val = Wr[i - 81920];
    else if (i < 98304) val = Wa[i - 90112];
    else if (i < 100352) val = Wq[i - 98304];
    else if (i < 102400) val = Wk[i - 100352];
    else val = Wv[i - 102400];
    Wb[i] = (__bf16)val;
}

// fused producer: a = relu(bn2(Wa@x)), then q/kT/V2 from a. All MFMA. (validated r16)
__global__ __launch_bounds__(256) void z_mega(
    const __bf16* __restrict__ xT, const __bf16* __restrict__ Wb,
    const float* __restrict__ ba, const float* __restrict__ g2, const float* __restrict__ b2,
    const float* __restrict__ m2, const float* __restrict__ v2,
    const float* __restrict__ bq, const float* __restrict__ bk, const float* __restrict__ bv,
    float* __restrict__ a, float* __restrict__ q, __bf16* __restrict__ kT, __bf16* __restrict__ V2)
{
    __shared__ __align__(16) __bf16 an[16 * 128];
    int tid = threadIdx.x;
    int b = blockIdx.x >> 8;
    int n0 = (blockIdx.x & 255) * 16;
    int l = tid & 63, w = tid >> 6;
    int lm = l & 15, g = l >> 4;

    const __bf16* Wa2 = Wb + 90112;
    const __bf16* Wq2 = Wb + 98304;
    const __bf16* Wk2 = Wb + 100352;
    const __bf16* Wv2 = Wb + 102400;

    bf16x8 bx[2];
#pragma unroll
    for (int kc = 0; kc < 2; ++kc)
        bx[kc] = ((const bf16x8*)xT)[((size_t)b * NPIX + n0 + lm) * 8 + (kc * 4 + g)];
    f32x4 pa[2];
#pragma unroll
    for (int ct = 0; ct < 2; ++ct) {
#pragma unroll
        for (int r = 0; r < 4; ++r) pa[ct][r] = ba[w * 32 + ct * 16 + g * 4 + r];
#pragma unroll
        for (int kc = 0; kc < 2; ++kc) {
            bf16x8 afr = *(const bf16x8*)&Wa2[(size_t)(w * 32 + ct * 16 + lm) * 64 + kc * 32 + g * 8];
            pa[ct] = __builtin_amdgcn_mfma_f32_16x16x32_bf16(afr, bx[kc], pa[ct], 0, 0, 0);
        }
    }
#pragma unroll
    for (int ct = 0; ct < 2; ++ct) {
        bf16x4 pk;
#pragma unroll
        for (int r = 0; r < 4; ++r) {
            int co = w * 32 + ct * 16 + g * 4 + r;
            float sc = rsqrtf(v2[co] + EPS_) * g2[co];
            float sh = b2[co] - m2[co] * sc;
            float y = fmaxf(pa[ct][r] * sc + sh, 0.f);
            a[((size_t)b * CO_ + co) * NPIX + n0 + lm] = y;
            pk[r] = (__bf16)y;
        }
        int co8 = w * 4 + ct * 2 + (g >> 1);
        int ch = co8 ^ (lm & 7);
        *(bf16x4*)&an[lm * 128 + ch * 8 + (g & 1) * 4] = pk;
    }
    __syncthreads();

    bf16x8 bn[4];
#pragma unroll
    for (int kc = 0; kc < 4; ++kc) {
        int ch = (kc * 4 + g) ^ (lm & 7);
        bn[kc] = *(const bf16x8*)&an[lm * 128 + ch * 8];
    }
    f32x4 pv[2];
#pragma unroll
    for (int ct = 0; ct < 2; ++ct) {
#pragma unroll
        for (int r = 0; r < 4; ++r) pv[ct][r] = bv[w * 32 + ct * 16 + g * 4 + r];
#pragma unroll
        for (int kc = 0; kc < 4; ++kc) {
            bf16x8 afr = *(const bf16x8*)&Wv2[(size_t)(w * 32 + ct * 16 + lm) * 128 + kc * 32 + g * 8];
            pv[ct] = __builtin_amdgcn_mfma_f32_16x16x32_bf16(afr, bn[kc], pv[ct], 0, 0, 0);
        }
    }
    int n = n0 + lm;
#pragma unroll
    for (int ct = 0; ct < 2; ++ct)
#pragma unroll
        for (int r = 0; r < 4; ++r) {
            int c = w * 32 + ct * 16 + g * 4 + r;
            V2[(size_t)b * 524288 + (size_t)(n >> 3) * 1024 + c * 8 + (n & 7)] = (__bf16)pv[ct][r];
        }
    if (w == 0) {
        f32x4 pq;
#pragma unroll
        for (int r = 0; r < 4; ++r) pq[r] = bq[g * 4 + r];
#pragma unroll
        for (int kc = 0; kc < 4; ++kc) {
            bf16x8 afr = *(const bf16x8*)&Wq2[(size_t)lm * 128 + kc * 32 + g * 8];
            pq = __builtin_amdgcn_mfma_f32_16x16x32_bf16(afr, bn[kc], pq, 0, 0, 0);
        }
#pragma unroll
        for (int r = 0; r < 4; ++r)
            q[((size_t)b * CQ_ + g * 4 + r) * NPIX + n] = pq[r];
    } else if (w == 1) {
        f32x4 pk2;
#pragma unroll
        for (int r = 0; r < 4; ++r) pk2[r] = bk[g * 4 + r];
#pragma unroll
        for (int kc = 0; kc < 4; ++kc) {
            bf16x8 afr = *(const bf16x8*)&Wk2[(size_t)lm * 128 + kc * 32 + g * 8];
            pk2 = __builtin_amdgcn_mfma_f32_16x16x32_bf16(afr, bn[kc], pk2, 0, 0, 0);
        }
        bf16x4 kk;
#pragma unroll
        for (int r = 0; r < 4; ++r) kk[r] = (__bf16)pk2[r];
        *(bf16x4*)&kT[((size_t)b * NPIX + n) * CQ_ + g * 4] = kk;
    }
}

// MFMA implicit-GEMM conv3x3 + BN + ReLU (validated)
__global__ __launch_bounds__(256) void z_conv3m(
    const __bf16* __restrict__ xT, const __bf16* __restrict__ Wt2,
    const float* __restrict__ b3, const float* __restrict__ g,
    const float* __restrict__ bb, const float* __restrict__ m,
    const float* __restrict__ v, float* __restrict__ local)
{
    __shared__ __align__(16) __bf16 xt[3 * 66 * 64];
    __shared__ __align__(16) __bf16 wt[32 * 576];
    __shared__ float scs[32], shs[32];

    int blk = blockIdx.x;
    int b = blk >> 8;
    int h = (blk >> 2) & 63;
    int cg = blk & 3;
    int co0 = cg * 32;
    int tid = threadIdx.x;
    int l = tid & 63;
    int nt = tid >> 6;
    int lm = l & 15, lh = l >> 4;

    if (tid < 32) {
        int co = co0 + tid;
        float scv = rsqrtf(v[co] + EPS_) * g[co];
        scs[tid] = scv;
        shs[tid] = (b3[co] - m[co]) * scv + bb[co];
    }

    const bf16x8* xs = (const bf16x8*)xT + (size_t)b * (NPIX * 8);
    for (int i = tid; i < 1584; i += 256) {
        int r = i / 528;
        int rem = i - r * 528;
        int c = rem >> 3;
        int cig = rem & 7;
        int hh = h + r - 1;
        int gc = c - 1;
        bf16x8 val;
#pragma unroll
        for (int j = 0; j < 8; ++j) val[j] = (__bf16)0.f;
        if ((unsigned)hh < 64u && (unsigned)gc < 64u)
            val = xs[(hh * 64 + gc) * 8 + cig];
        *(bf16x8*)&xt[(r * 66 + c) * 64 + ((cig ^ (c & 7)) * 8)] = val;
    }
    const bf16x8* wsrc = (const bf16x8*)Wt2 + (size_t)co0 * 72;
    for (int i = tid; i < 2304; i += 256) {
        int co = i / 72;
        int kc = i - co * 72;
        *(bf16x8*)&wt[co * 576 + ((kc ^ (co & 7)) * 8)] = wsrc[i];
    }
    __syncthreads();

    f32x4 acc0 = {0.f, 0.f, 0.f, 0.f};
    f32x4 acc1 = {0.f, 0.f, 0.f, 0.f};
#pragma unroll
    for (int tap = 0; tap < 9; ++tap) {
        int dh = tap / 3, dw = tap % 3;
#pragma unroll
        for (int ks = 0; ks < 2; ++ks) {
            int cig = ks * 4 + lh;
            int col = nt * 16 + lm + dw;
            bf16x8 bfr = *(const bf16x8*)&xt[(dh * 66 + col) * 64 + ((cig ^ (col & 7)) * 8)];
            int kcg = tap * 8 + cig;
            bf16x8 a0 = *(const bf16x8*)&wt[lm * 576 + ((kcg ^ (lm & 7)) * 8)];
            bf16x8 a1 = *(const bf16x8*)&wt[(16 + lm) * 576 + ((kcg ^ (lm & 7)) * 8)];
            acc0 = __builtin_amdgcn_mfma_f32_16x16x32_bf16(a0, bfr, acc0, 0, 0, 0);
            acc1 = __builtin_amdgcn_mfma_f32_16x16x32_bf16(a1, bfr, acc1, 0, 0, 0);
        }
    }

    size_t obase = (size_t)b * CO_ * NPIX + h * 64 + nt * 16 + lm;
#pragma unroll
    for (int r = 0; r < 4; ++r) {
        int cl0 = lh * 4 + r;
        float y0 = fmaxf(acc0[r] * scs[cl0] + shs[cl0], 0.f);
        local[obase + (size_t)(co0 + cl0) * NPIX] = y0;
        int cl1 = 16 + cl0;
        float y1 = fmaxf(acc1[r] * scs[cl1] + shs[cl1], 0.f);
        local[obase + (size_t)(co0 + cl1) * NPIX] = y1;
    }
}

// split-KV MFMA flash attention: attn4 inner loop, half KV range per block.
// grid 2048: b(2) | half(1) | qtile(8). Writes self-normalized o (bf16) + (m,l).
__global__ __launch_bounds__(256) void z_attn4s(
    const float* __restrict__ q, const __bf16* __restrict__ kT, const __bf16* __restrict__ V2,
    __bf16* __restrict__ o_part, float2* __restrict__ ml)
{
    __shared__ __align__(16) unsigned char smem[8704];
    __shared__ float wmax[4][16], wsum[4][16], fs[16];
    __bf16* p_lds = (__bf16*)smem;
    float* o_lds = (float*)smem;

    int tid = threadIdx.x;
    int b = blockIdx.x >> 9;
    int half = (blockIdx.x >> 8) & 1;
    int q0 = (blockIdx.x & 255) * 16;
    int l = tid & 63;
    int w = tid >> 6;
    int lm = l & 15;
    int g = l >> 4;

    bf16x8 qfrag;
#pragma unroll
    for (int j = 0; j < 8; ++j) qfrag[j] = (__bf16)0.f;
    if (g < 2) {
#pragma unroll
        for (int j = 0; j < 8; ++j)
            qfrag[j] = (__bf16)q[((size_t)b * CQ_ + g * 8 + j) * NPIX + q0 + lm];
    }

    float m_run = -1e30f, l_run = 0.f;
    f32x4 acc0 = {0.f, 0.f, 0.f, 0.f};
    f32x4 acc1 = {0.f, 0.f, 0.f, 0.f};
    int c0 = w * 32 + lm;
    int c1 = c0 + 16;
    const bf16x8* vbase = (const bf16x8*)V2 + (size_t)b * 65536;
    const __bf16* ktb = kT + (size_t)b * NPIX * CQ_;

    for (int t = 0; t < 8; ++t) {
        int m0 = half * 2048 + t * 256;
        f32x4 sfr[4];
#pragma unroll
        for (int ms = 0; ms < 4; ++ms) {
            bf16x8 kf;
#pragma unroll
            for (int j = 0; j < 8; ++j) kf[j] = (__bf16)0.f;
            if (g < 2)
                kf = *(const bf16x8*)&ktb[(size_t)(m0 + w * 64 + ms * 16 + lm) * CQ_ + g * 8];
            f32x4 zz = {0.f, 0.f, 0.f, 0.f};
            sfr[ms] = __builtin_amdgcn_mfma_f32_16x16x32_bf16(kf, qfrag, zz, 0, 0, 0);
        }
        float pmax = -1e30f;
#pragma unroll
        for (int ms = 0; ms < 4; ++ms)
#pragma unroll
            for (int r = 0; r < 4; ++r) pmax = fmaxf(pmax, sfr[ms][r]);
        pmax = fmaxf(pmax, __shfl_xor(pmax, 16));
        pmax = fmaxf(pmax, __shfl_xor(pmax, 32));
        if (g == 0) wmax[w][lm] = pmax;
        __syncthreads();
        float tmax = fmaxf(fmaxf(wmax[0][lm], wmax[1][lm]), fmaxf(wmax[2][lm], wmax[3][lm]));
        float nm = fmaxf(m_run, tmax);
        float f = __expf(m_run - nm);
        m_run = nm;
        if (w == 0 && g == 0) fs[lm] = f;
        float psum = 0.f;
#pragma unroll
        for (int ms = 0; ms < 4; ++ms) {
            float p0 = __expf(sfr[ms][0] - nm);
            float p1 = __expf(sfr[ms][1] - nm);
            float p2 = __expf(sfr[ms][2] - nm);
            float p3 = __expf(sfr[ms][3] - nm);
            psum += (p0 + p1) + (p2 + p3);
            bf16x4 pk;
            pk[0] = (__bf16)p0; pk[1] = (__bf16)p1; pk[2] = (__bf16)p2; pk[3] = (__bf16)p3;
            *(bf16x4*)&p_lds[lm * 264 + w * 64 + ms * 16 + g * 4] = pk;
        }
        psum += __shfl_xor(psum, 16);
        psum += __shfl_xor(psum, 32);
        if (g == 0) wsum[w][lm] = psum;
        __syncthreads();
        float tsum = (wsum[0][lm] + wsum[1][lm]) + (wsum[2][lm] + wsum[3][lm]);
        l_run = l_run * f + tsum;
        float f0 = fs[g * 4 + 0], f1 = fs[g * 4 + 1], f2 = fs[g * 4 + 2], f3 = fs[g * 4 + 3];
        acc0[0] *= f0; acc0[1] *= f1; acc0[2] *= f2; acc0[3] *= f3;
        acc1[0] *= f0; acc1[1] *= f1; acc1[2] *= f2; acc1[3] *= f3;
#pragma unroll
        for (int ks = 0; ks < 8; ++ks) {
            bf16x8 afrag = *(const bf16x8*)&p_lds[lm * 264 + ks * 32 + g * 8];
            int msv = (m0 >> 3) + ks * 4 + g;
            bf16x8 bf0 = vbase[msv * 128 + c0];
            bf16x8 bf1 = vbase[msv * 128 + c1];
            acc0 = __builtin_amdgcn_mfma_f32_16x16x32_bf16(afrag, bf0, acc0, 0, 0, 0);
            acc1 = __builtin_amdgcn_mfma_f32_16x16x32_bf16(afrag, bf1, acc1, 0, 0, 0);
        }
        __syncthreads();
    }

#pragma unroll
    for (int r = 0; r < 4; ++r) {
        int qrow = g * 4 + r;
        o_lds[c0 * 17 + qrow] = acc0[r];
        o_lds[c1 * 17 + qrow] = acc1[r];
    }
    if (w == 0 && g == 0)
        ml[(size_t)(half * 4 + b) * NPIX + q0 + lm] = make_float2(m_run, l_run);
    __syncthreads();
    int qi = tid & 15;
    float inv = 1.f / l_run;
#pragma unroll
    for (int j = 0; j < 8; ++j) {
        int cc = (tid >> 4) + 16 * j;
        size_t idx = ((size_t)(half * 4 + b) * CO_ + cc) * NPIX + q0 + qi;
        o_part[idx] = (__bf16)(o_lds[cc * 17 + qi] * inv);
    }
}

// combine two KV halves: attn = gam * merged_o + a
__global__ __launch_bounds__(256) void z_acomb(
    const __bf16* __restrict__ o_part, const float2* __restrict__ ml,
    const float* __restrict__ a, const float* __restrict__ gamp, float* __restrict__ attn)
{
    int i = blockIdx.x * 256 + threadIdx.x;   // B*CO*1024
    int n4 = (i & 1023) * 4;
    int co = (i >> 10) & (CO_ - 1);
    int b = i >> 17;
    float gam = gamp[0];
    bf16x4 o1 = *(const bf16x4*)&o_part[((size_t)b * CO_ + co) * NPIX + n4];
    bf16x4 o2 = *(const bf16x4*)&o_part[((size_t)(4 + b) * CO_ + co) * NPIX + n4];
    float4 av = *(const float4*)(a + ((size_t)b * CO_ + co) * NPIX + n4);
    float r[4], ai[4] = {av.x, av.y, av.z, av.w};
#pragma unroll
    for (int e = 0; e < 4; ++e) {
        float2 m1 = ml[(size_t)b * NPIX + n4 + e];
        float2 m2 = ml[(size_t)(4 + b) * NPIX + n4 + e];
        float mm = fmaxf(m1.x, m2.x);
        float w1 = m1.y * __expf(m1.x - mm);
        float w2 = m2.y * __expf(m2.x - mm);
        float o = ((float)o1[e] * w1 + (float)o2[e] * w2) / (w1 + w2);
        r[e] = gam * o + ai[e];
    }
    float4 rv = {r[0], r[1], r[2], r[3]};
    *(float4*)(attn + ((size_t)b * CO_ + co) * NPIX + n4) = rv;
}

// fused gate + final, MFMA everywhere (validated)
__global__ __launch_bounds__(256) void z_fuseout2(
    const float* __restrict__ local, const float* __restrict__ attn, const float* __restrict__ x,
    const __bf16* __restrict__ Wb,
    const float* __restrict__ bg, const float* __restrict__ g3, const float* __restrict__ b3n,
    const float* __restrict__ m3, const float* __restrict__ v3,
    const float* __restrict__ bfb, const float* __restrict__ g4, const float* __restrict__ b4,
    const float* __restrict__ m4, const float* __restrict__ v4,
    const float* __restrict__ rsp, float* __restrict__ out)
{
    __shared__ __align__(16) unsigned char smem[32768 + 4096];
    __bf16* sb2 = (__bf16*)smem;
    __bf16* sxT = (__bf16*)(smem + 28672);

    int tid = threadIdx.x;
    int b = blockIdx.x >> 7;
    int n0 = (blockIdx.x & 127) * 32;

#pragma unroll
    for (int p = 0; p < 4; ++p) {
        int idx = p * 256 + tid;
        int c = idx >> 3, j = idx & 7;
        float lv[4], av[4];
        *(float4*)lv = *(const float4*)(local + ((size_t)b * CO_ + c) * NPIX + n0 + j * 4);
        *(float4*)av = *(const float4*)(attn + ((size_t)b * CO_ + c) * NPIX + n0 + j * 4);
#pragma unroll
        for (int e = 0; e < 4; ++e) {
            int n = j * 4 + e;
            int k1 = 128 + c, k2 = 256 + c;
            sb2[n * 448 + (((k1 >> 3) ^ (n & 7)) << 3) + (k1 & 7)] = (__bf16)lv[e];
            sb2[n * 448 + (((k2 >> 3) ^ (n & 7)) << 3) + (k2 & 7)] = (__bf16)av[e];
        }
    }
#pragma unroll
    for (int p = 0; p < 2; ++p) {
        int idx = p * 256 + tid;
        int c = idx >> 3, j = idx & 7;
        float xv[4];
        *(float4*)xv = *(const float4*)(x + ((size_t)b * CI_ + c) * NPIX + n0 + j * 4);
#pragma unroll
        for (int e = 0; e < 4; ++e) {
            int n = j * 4 + e;
            sxT[n * 64 + (((c >> 3) ^ (n & 7)) << 3) + (c & 7)] = (__bf16)xv[e];
        }
    }
    __syncthreads();

    int l = tid & 63, w = tid >> 6;
    int lm = l & 15, g = l >> 4;
    int co0 = w * 32;
    int t7 = lm & 7;

    f32x4 p1[2][2];
#pragma unroll
    for (int cs = 0; cs < 2; ++cs) {
        float bv = bg[co0 + cs * 16 + lm];
#pragma unroll
        for (int ns = 0; ns < 2; ++ns) {
            p1[ns][cs][0] = bv; p1[ns][cs][1] = bv; p1[ns][cs][2] = bv; p1[ns][cs][3] = bv;
        }
    }
    const __bf16* Wg2 = Wb;
#pragma unroll
    for (int kc = 0; kc < 8; ++kc) {
        int ch = (16 + kc * 4 + g) ^ t7;
        bf16x8 a0 = *(const bf16x8*)&sb2[lm * 448 + ch * 8];
        bf16x8 a1 = *(const bf16x8*)&sb2[(16 + lm) * 448 + ch * 8];
        bf16x8 b0 = *(const bf16x8*)&Wg2[(size_t)(co0 + lm) * 256 + kc * 32 + g * 8];
        bf16x8 b1 = *(const bf16x8*)&Wg2[(size_t)(co0 + 16 + lm) * 256 + kc * 32 + g * 8];
        p1[0][0] = __builtin_amdgcn_mfma_f32_16x16x32_bf16(a0, b0, p1[0][0], 0, 0, 0);
        p1[0][1] = __builtin_amdgcn_mfma_f32_16x16x32_bf16(a0, b1, p1[0][1], 0, 0, 0);
        p1[1][0] = __builtin_amdgcn_mfma_f32_16x16x32_bf16(a1, b0, p1[1][0], 0, 0, 0);
        p1[1][1] = __builtin_amdgcn_mfma_f32_16x16x32_bf16(a1, b1, p1[1][1], 0, 0, 0);
    }
#pragma unroll
    for (int cs = 0; cs < 2; ++cs) {
        int co = co0 + cs * 16 + lm;
        float sc3 = rsqrtf(v3[co] + EPS_) * g3[co];
        float sh3 = b3n[co] - m3[co] * sc3;
        int kl = 128 + co, ka = 256 + co;
#pragma unroll
        for (int ns = 0; ns < 2; ++ns)
#pragma unroll
            for (int r = 0; r < 4; ++r) {
                int n = ns * 16 + g * 4 + r;
                float z = p1[ns][cs][r] * sc3 + sh3;
                float gate = 1.f / (1.f + __expf(-z));
                float lv = (float)sb2[n * 448 + (((kl >> 3) ^ (n & 7)) << 3) + (kl & 7)];
                float av = (float)sb2[n * 448 + (((ka >> 3) ^ (n & 7)) << 3) + (ka & 7)];
                float fu = gate * lv + (1.f - gate) * av;
                sb2[n * 448 + (((co >> 3) ^ (n & 7)) << 3) + (co & 7)] = (__bf16)fu;
            }
    }
    __syncthreads();

    f32x4 p2[2][2], pr[2][2];
#pragma unroll
    for (int cs = 0; cs < 2; ++cs) {
        float bv = bfb[co0 + cs * 16 + lm];
#pragma unroll
        for (int ns = 0; ns < 2; ++ns) {
            p2[ns][cs][0] = bv; p2[ns][cs][1] = bv; p2[ns][cs][2] = bv; p2[ns][cs][3] = bv;
            pr[ns][cs] = (f32x4){0.f, 0.f, 0.f, 0.f};
        }
    }
    const __bf16* Wf2 = Wb + 32768;
    const __bf16* Wr2 = Wb + 81920;
#pragma unroll
    for (int kc = 0; kc < 12; ++kc) {
        int ch = (kc * 4 + g) ^ t7;
        bf16x8 a0 = *(const bf16x8*)&sb2[lm * 448 + ch * 8];
        bf16x8 a1 = *(const bf16x8*)&sb2[(16 + lm) * 448 + ch * 8];
        bf16x8 b0 = *(const bf16x8*)&Wf2[(size_t)(co0 + lm) * 384 + kc * 32 + g * 8];
        bf16x8 b1 = *(const bf16x8*)&Wf2[(size_t)(co0 + 16 + lm) * 384 + kc * 32 + g * 8];
        p2[0][0] = __builtin_amdgcn_mfma_f32_16x16x32_bf16(a0, b0, p2[0][0], 0, 0, 0);
        p2[0][1] = __builtin_amdgcn_mfma_f32_16x16x32_bf16(a0, b1, p2[0][1], 0, 0, 0);
        p2[1][0] = __builtin_amdgcn_mfma_f32_16x16x32_bf16(a1, b0, p2[1][0], 0, 0, 0);
        p2[1][1] = __builtin_amdgcn_mfma_f32_16x16x32_bf16(a1, b1, p2[1][1], 0, 0, 0);
    }
#pragma unroll
    for (int kc = 0; kc < 2; ++kc) {
        int ch = (kc * 4 + g) ^ t7;
        bf16x8 a0 = *(const bf16x8*)&sxT[lm * 64 + ch * 8];
        bf16x8 a1 = *(const bf16x8*)&sxT[(16 + lm) * 64 + ch * 8];
        bf16x8 b0 = *(const bf16x8*)&Wr2[(size_t)(co0 + lm) * 64 + kc * 32 + g * 8];
        bf16x8 b1 = *(const bf16x8*)&Wr2[(size_t)(co0 + 16 + lm) * 64 + kc * 32 + g * 8];
        pr[0][0] = __builtin_amdgcn_mfma_f32_16x16x32_bf16(a0, b0, pr[0][0], 0, 0, 0);
        pr[0][1] = __builtin_amdgcn_mfma_f32_16x16x32_bf16(a0, b1, pr[0][1], 0, 0, 0);
        pr[1][0] = __builtin_amdgcn_mfma_f32_16x16x32_bf16(a1, b0, pr[1][0], 0, 0, 0);
        pr[1][1] = __builtin_amdgcn_mfma_f32_16x16x32_bf16(a1, b1, pr[1][1], 0, 0, 0);
    }
    __syncthreads();

    float* o_lds = (float*)smem;   // [128][36]
    float rsv = rsp[0];
#pragma unroll
    for (int cs = 0; cs < 2; ++cs) {
        int co = co0 + cs * 16 + lm;
        float sc4 = rsqrtf(v4[co] + EPS_) * g4[co];
        float sh4 = b4[co] - m4[co] * sc4;
#pragma unroll
        for (int ns = 0; ns < 2; ++ns)
#pragma unroll
            for (int r = 0; r < 4; ++r) {
                int n = ns * 16 + g * 4 + r;
                float o = fmaxf(p2[ns][cs][r] * sc4 + sh4, 0.f) + rsv * pr[ns][cs][r];
                o_lds[co * 36 + n] = o;
            }
    }
    __syncthreads();
    {
        int c = tid >> 1, h = tid & 1;
#pragma unroll
        for (int j2 = 0; j2 < 4; ++j2) {
            float4 vv = *(float4*)&o_lds[c * 36 + h * 16 + j2 * 4];
            *(float4*)(out + ((size_t)b * CO_ + c) * NPIX + n0 + h * 16 + j2 * 4) = vv;
        }
    }
}

extern "C" void kernel_launch(void* const* d_in, const int* in_sizes, int n_in,
                              void* d_out, int out_size, void* d_ws, size_t ws_size,
                              hipStream_t stream) {
    const float* x   = (const float*)d_in[0];
    const float* W3  = (const float*)d_in[1];
    const float* b3  = (const float*)d_in[2];
    const float* g1  = (const float*)d_in[3];
    const float* b1  = (const float*)d_in[4];
    const float* m1  = (const float*)d_in[5];
    const float* v1  = (const float*)d_in[6];
    const float* Wa  = (const float*)d_in[7];
    const float* ba  = (const float*)d_in[8];
    const float* g2  = (const float*)d_in[9];
    const float* b2  = (const float*)d_in[10];
    const float* m2  = (const float*)d_in[11];
    const float* v2  = (const float*)d_in[12];
    const float* Wq  = (const float*)d_in[13];
    const float* bq  = (const float*)d_in[14];
    const float* Wk  = (const float*)d_in[15];
    const float* bk  = (const float*)d_in[16];
    const float* Wv  = (const float*)d_in[17];
    const float* bv  = (const float*)d_in[18];
    const float* gam = (const float*)d_in[19];
    const float* Wg  = (const float*)d_in[20];
    const float* bg  = (const float*)d_in[21];
    const float* g3  = (const float*)d_in[22];
    const float* b3n = (const float*)d_in[23];
    const float* m3  = (const float*)d_in[24];
    const float* v3  = (const float*)d_in[25];
    const float* Wf  = (const float*)d_in[26];
    const float* bfb = (const float*)d_in[27];
    const float* g4  = (const float*)d_in[28];
    const float* b4  = (const float*)d_in[29];
    const float* m4  = (const float*)d_in[30];
    const float* v4  = (const float*)d_in[31];
    const float* Wr  = (const float*)d_in[32];
    const float* rs  = (const float*)d_in[33];

    float* ws    = (float*)d_ws;
    float* a_    = ws;                       // [0, 2M)
    float* local = ws + 2097152;             // [2M, 4M)
    float* attn  = ws + 4194304;             // [4M, 6M)
    __bf16* V2   = (__bf16*)(ws + 6291456);  // 4 MB bf16
    float* q     = ws + 7340032;             // 262,144 floats
    __bf16* kT   = (__bf16*)(ws + 7602176);  // 512 KB bf16
    __bf16* xT   = (__bf16*)(ws + 7864320);  // 2 MB bf16
    __bf16* Wt2  = (__bf16*)(ws + 8388608);  // 147 KB bf16
    __bf16* Wb   = (__bf16*)(ws + 8450048);  // 232 KB bf16
    __bf16* o_part = (__bf16*)(ws + 8509440);  // 2 x B x CO x N bf16 = 8 MB
    float2* ml   = (float2*)(ws + 10606592);   // 2 x B x N float2 = 256 KB
    // total ≈ 42.7 MB

    float* out = (float*)d_out;

    z_prepx<<<256, 256, 0, stream>>>(x, xT);
    z_prepw<<<288, 256, 0, stream>>>(W3, Wt2);
    z_prepfw2<<<464, 256, 0, stream>>>(Wg, Wf, Wr, Wa, Wq, Wk, Wv, Wb);
    z_mega<<<1024, 256, 0, stream>>>(xT, Wb, ba, g2, b2, m2, v2, bq, bk, bv, a_, q, kT, V2);
    z_attn4s<<<2048, 256, 0, stream>>>(q, kT, V2, o_part, ml);
    z_acomb<<<2048, 256, 0, stream>>>(o_part, ml, a_, gam, attn);
    z_conv3m<<<1024, 256, 0, stream>>>(xT, Wt2, b3, g1, b1, m1, v1, local);
    z_fuseout2<<<512, 256, 0, stream>>>(local, attn, x, Wb, bg, g3, b3n, m3, v3,
                                        bfb, g4, b4, m4, v4, rs, out);
}

// Round 18
// 112.850 us; speedup vs baseline: 1.0859x; 1.0859x over previous
//
#include <hip/hip_runtime.h>
#include <hip/hip_bf16.h>

#define CI_ 64
#define CO_ 128
#define NPIX 4096
#define CQ_ 16
#define EPS_ 1e-5f

typedef __attribute__((ext_vector_type(8))) __bf16 bf16x8;
typedef __attribute__((ext_vector_type(4))) __bf16 bf16x4;
typedef __attribute__((ext_vector_type(4))) float f32x4;

// transpose x -> xT[b][n][ci] bf16
__global__ __launch_bounds__(256) void z_prepx(
    const float* __restrict__ x, __bf16* __restrict__ xT)
{
    __shared__ float tl[64][65];
    int b = blockIdx.x >> 6;
    int n0 = (blockIdx.x & 63) * 64;
    int tid = threadIdx.x;
    int nn = tid & 63, c4 = tid >> 6;
#pragma unroll
    for (int p = 0; p < 16; ++p) {
        int ci = p * 4 + c4;
        tl[ci][nn] = x[((size_t)b * CI_ + ci) * NPIX + n0 + nn];
    }
    __syncthreads();
#pragma unroll
    for (int p = 0; p < 2; ++p) {
        int idx = p * 256 + tid;
        int n = idx >> 3, cig = idx & 7;
        bf16x8 vv;
#pragma unroll
        for (int j = 0; j < 8; ++j) vv[j] = (__bf16)tl[cig * 8 + j][n];
        ((bf16x8*)xT)[((size_t)b * NPIX + n0 + n) * 8 + cig] = vv;
    }
}

// fused weight prep: W3 -> Wt2 (73728), and Wg|Wf|Wr|Wa|Wq|Wk|Wv -> Wb (118784)
__global__ __launch_bounds__(256) void z_prepw2(
    const float* __restrict__ W3, __bf16* __restrict__ Wt2,
    const float* __restrict__ Wg, const float* __restrict__ Wf, const float* __restrict__ Wr,
    const float* __restrict__ Wa, const float* __restrict__ Wq, const float* __restrict__ Wk,
    const float* __restrict__ Wv, __bf16* __restrict__ Wb)
{
    int i = blockIdx.x * 256 + threadIdx.x;
    if (i < 73728) {
        int co = i / 576;
        int r = i - co * 576;
        int tap = r >> 6;
        int ci = r & 63;
        Wt2[i] = (__bf16)W3[((size_t)co * CI_ + ci) * 9 + tap];
    }
    if (i < 118784) {
        float val;
        if (i < 32768) val = Wg[i];
        else if (i < 81920) val = Wf[i - 32768];
        else if (i < 90112) val = Wr[i - 81920];
        else if (i < 98304) val = Wa[i - 90112];
        else if (i < 100352) val = Wq[i - 98304];
        else if (i < 102400) val = Wk[i - 100352];
        else val = Wv[i - 102400];
        Wb[i] = (__bf16)val;
    }
}

// fused producer: a = relu(bn2(Wa@x)), then q/kT/V2 from a. All MFMA. (validated r16)
__global__ __launch_bounds__(256) void z_mega(
    const __bf16* __restrict__ xT, const __bf16* __restrict__ Wb,
    const float* __restrict__ ba, const float* __restrict__ g2, const float* __restrict__ b2,
    const float* __restrict__ m2, const float* __restrict__ v2,
    const float* __restrict__ bq, const float* __restrict__ bk, const float* __restrict__ bv,
    float* __restrict__ a, float* __restrict__ q, __bf16* __restrict__ kT, __bf16* __restrict__ V2)
{
    __shared__ __align__(16) __bf16 an[16 * 128];
    int tid = threadIdx.x;
    int b = blockIdx.x >> 8;
    int n0 = (blockIdx.x & 255) * 16;
    int l = tid & 63, w = tid >> 6;
    int lm = l & 15, g = l >> 4;

    const __bf16* Wa2 = Wb + 90112;
    const __bf16* Wq2 = Wb + 98304;
    const __bf16* Wk2 = Wb + 100352;
    const __bf16* Wv2 = Wb + 102400;

    bf16x8 bx[2];
#pragma unroll
    for (int kc = 0; kc < 2; ++kc)
        bx[kc] = ((const bf16x8*)xT)[((size_t)b * NPIX + n0 + lm) * 8 + (kc * 4 + g)];
    f32x4 pa[2];
#pragma unroll
    for (int ct = 0; ct < 2; ++ct) {
#pragma unroll
        for (int r = 0; r < 4; ++r) pa[ct][r] = ba[w * 32 + ct * 16 + g * 4 + r];
#pragma unroll
        for (int kc = 0; kc < 2; ++kc) {
            bf16x8 afr = *(const bf16x8*)&Wa2[(size_t)(w * 32 + ct * 16 + lm) * 64 + kc * 32 + g * 8];
            pa[ct] = __builtin_amdgcn_mfma_f32_16x16x32_bf16(afr, bx[kc], pa[ct], 0, 0, 0);
        }
    }
#pragma unroll
    for (int ct = 0; ct < 2; ++ct) {
        bf16x4 pk;
#pragma unroll
        for (int r = 0; r < 4; ++r) {
            int co = w * 32 + ct * 16 + g * 4 + r;
            float sc = rsqrtf(v2[co] + EPS_) * g2[co];
            float sh = b2[co] - m2[co] * sc;
            float y = fmaxf(pa[ct][r] * sc + sh, 0.f);
            a[((size_t)b * CO_ + co) * NPIX + n0 + lm] = y;
            pk[r] = (__bf16)y;
        }
        int co8 = w * 4 + ct * 2 + (g >> 1);
        int ch = co8 ^ (lm & 7);
        *(bf16x4*)&an[lm * 128 + ch * 8 + (g & 1) * 4] = pk;
    }
    __syncthreads();

    bf16x8 bn[4];
#pragma unroll
    for (int kc = 0; kc < 4; ++kc) {
        int ch = (kc * 4 + g) ^ (lm & 7);
        bn[kc] = *(const bf16x8*)&an[lm * 128 + ch * 8];
    }
    f32x4 pv[2];
#pragma unroll
    for (int ct = 0; ct < 2; ++ct) {
#pragma unroll
        for (int r = 0; r < 4; ++r) pv[ct][r] = bv[w * 32 + ct * 16 + g * 4 + r];
#pragma unroll
        for (int kc = 0; kc < 4; ++kc) {
            bf16x8 afr = *(const bf16x8*)&Wv2[(size_t)(w * 32 + ct * 16 + lm) * 128 + kc * 32 + g * 8];
            pv[ct] = __builtin_amdgcn_mfma_f32_16x16x32_bf16(afr, bn[kc], pv[ct], 0, 0, 0);
        }
    }
    int n = n0 + lm;
#pragma unroll
    for (int ct = 0; ct < 2; ++ct)
#pragma unroll
        for (int r = 0; r < 4; ++r) {
            int c = w * 32 + ct * 16 + g * 4 + r;
            V2[(size_t)b * 524288 + (size_t)(n >> 3) * 1024 + c * 8 + (n & 7)] = (__bf16)pv[ct][r];
        }
    if (w == 0) {
        f32x4 pq;
#pragma unroll
        for (int r = 0; r < 4; ++r) pq[r] = bq[g * 4 + r];
#pragma unroll
        for (int kc = 0; kc < 4; ++kc) {
            bf16x8 afr = *(const bf16x8*)&Wq2[(size_t)lm * 128 + kc * 32 + g * 8];
            pq = __builtin_amdgcn_mfma_f32_16x16x32_bf16(afr, bn[kc], pq, 0, 0, 0);
        }
#pragma unroll
        for (int r = 0; r < 4; ++r)
            q[((size_t)b * CQ_ + g * 4 + r) * NPIX + n] = pq[r];
    } else if (w == 1) {
        f32x4 pk2;
#pragma unroll
        for (int r = 0; r < 4; ++r) pk2[r] = bk[g * 4 + r];
#pragma unroll
        for (int kc = 0; kc < 4; ++kc) {
            bf16x8 afr = *(const bf16x8*)&Wk2[(size_t)lm * 128 + kc * 32 + g * 8];
            pk2 = __builtin_amdgcn_mfma_f32_16x16x32_bf16(afr, bn[kc], pk2, 0, 0, 0);
        }
        bf16x4 kk;
#pragma unroll
        for (int r = 0; r < 4; ++r) kk[r] = (__bf16)pk2[r];
        *(bf16x4*)&kT[((size_t)b * NPIX + n) * CQ_ + g * 4] = kk;
    }
}

// MFMA implicit-GEMM conv3x3 + BN + ReLU (validated)
__global__ __launch_bounds__(256) void z_conv3m(
    const __bf16* __restrict__ xT, const __bf16* __restrict__ Wt2,
    const float* __restrict__ b3, const float* __restrict__ g,
    const float* __restrict__ bb, const float* __restrict__ m,
    const float* __restrict__ v, float* __restrict__ local)
{
    __shared__ __align__(16) __bf16 xt[3 * 66 * 64];
    __shared__ __align__(16) __bf16 wt[32 * 576];
    __shared__ float scs[32], shs[32];

    int blk = blockIdx.x;
    int b = blk >> 8;
    int h = (blk >> 2) & 63;
    int cg = blk & 3;
    int co0 = cg * 32;
    int tid = threadIdx.x;
    int l = tid & 63;
    int nt = tid >> 6;
    int lm = l & 15, lh = l >> 4;

    if (tid < 32) {
        int co = co0 + tid;
        float scv = rsqrtf(v[co] + EPS_) * g[co];
        scs[tid] = scv;
        shs[tid] = (b3[co] - m[co]) * scv + bb[co];
    }

    const bf16x8* xs = (const bf16x8*)xT + (size_t)b * (NPIX * 8);
    for (int i = tid; i < 1584; i += 256) {
        int r = i / 528;
        int rem = i - r * 528;
        int c = rem >> 3;
        int cig = rem & 7;
        int hh = h + r - 1;
        int gc = c - 1;
        bf16x8 val;
#pragma unroll
        for (int j = 0; j < 8; ++j) val[j] = (__bf16)0.f;
        if ((unsigned)hh < 64u && (unsigned)gc < 64u)
            val = xs[(hh * 64 + gc) * 8 + cig];
        *(bf16x8*)&xt[(r * 66 + c) * 64 + ((cig ^ (c & 7)) * 8)] = val;
    }
    const bf16x8* wsrc = (const bf16x8*)Wt2 + (size_t)co0 * 72;
    for (int i = tid; i < 2304; i += 256) {
        int co = i / 72;
        int kc = i - co * 72;
        *(bf16x8*)&wt[co * 576 + ((kc ^ (co & 7)) * 8)] = wsrc[i];
    }
    __syncthreads();

    f32x4 acc0 = {0.f, 0.f, 0.f, 0.f};
    f32x4 acc1 = {0.f, 0.f, 0.f, 0.f};
#pragma unroll
    for (int tap = 0; tap < 9; ++tap) {
        int dh = tap / 3, dw = tap % 3;
#pragma unroll
        for (int ks = 0; ks < 2; ++ks) {
            int cig = ks * 4 + lh;
            int col = nt * 16 + lm + dw;
            bf16x8 bfr = *(const bf16x8*)&xt[(dh * 66 + col) * 64 + ((cig ^ (col & 7)) * 8)];
            int kcg = tap * 8 + cig;
            bf16x8 a0 = *(const bf16x8*)&wt[lm * 576 + ((kcg ^ (lm & 7)) * 8)];
            bf16x8 a1 = *(const bf16x8*)&wt[(16 + lm) * 576 + ((kcg ^ (lm & 7)) * 8)];
            acc0 = __builtin_amdgcn_mfma_f32_16x16x32_bf16(a0, bfr, acc0, 0, 0, 0);
            acc1 = __builtin_amdgcn_mfma_f32_16x16x32_bf16(a1, bfr, acc1, 0, 0, 0);
        }
    }

    size_t obase = (size_t)b * CO_ * NPIX + h * 64 + nt * 16 + lm;
#pragma unroll
    for (int r = 0; r < 4; ++r) {
        int cl0 = lh * 4 + r;
        float y0 = fmaxf(acc0[r] * scs[cl0] + shs[cl0], 0.f);
        local[obase + (size_t)(co0 + cl0) * NPIX] = y0;
        int cl1 = 16 + cl0;
        float y1 = fmaxf(acc1[r] * scs[cl1] + shs[cl1], 0.f);
        local[obase + (size_t)(co0 + cl1) * NPIX] = y1;
    }
}

// QT=32 split-KV MFMA flash attention: 2 q-tiles share every V2 load.
// grid 1024: b(4) | half(2) | qblk(128 of 32 queries).
__global__ __launch_bounds__(256) void z_attn8(
    const float* __restrict__ q, const __bf16* __restrict__ kT, const __bf16* __restrict__ V2,
    __bf16* __restrict__ o_part, float2* __restrict__ ml)
{
    __shared__ __align__(16) unsigned char smem[16896];   // pA | pB ; o_lds aliases
    __shared__ float wmaxA[4][16], wsumA[4][16], fsA[16];
    __shared__ float wmaxB[4][16], wsumB[4][16], fsB[16];
    __bf16* pA = (__bf16*)smem;
    __bf16* pB = (__bf16*)(smem + 8448);
    float* o_lds = (float*)smem;

    int tid = threadIdx.x;
    int b = blockIdx.x >> 8;
    int half = (blockIdx.x >> 7) & 1;
    int q0 = (blockIdx.x & 127) * 32;
    int l = tid & 63;
    int w = tid >> 6;
    int lm = l & 15;
    int g = l >> 4;

    bf16x8 qfA, qfB;
#pragma unroll
    for (int j = 0; j < 8; ++j) { qfA[j] = (__bf16)0.f; qfB[j] = (__bf16)0.f; }
    if (g < 2) {
#pragma unroll
        for (int j = 0; j < 8; ++j) {
            qfA[j] = (__bf16)q[((size_t)b * CQ_ + g * 8 + j) * NPIX + q0 + lm];
            qfB[j] = (__bf16)q[((size_t)b * CQ_ + g * 8 + j) * NPIX + q0 + 16 + lm];
        }
    }

    float mA = -1e30f, lA = 0.f, mB = -1e30f, lB = 0.f;
    f32x4 aA0 = {0.f,0.f,0.f,0.f}, aA1 = {0.f,0.f,0.f,0.f};
    f32x4 aB0 = {0.f,0.f,0.f,0.f}, aB1 = {0.f,0.f,0.f,0.f};
    int c0 = w * 32 + lm;
    int c1 = c0 + 16;
    const bf16x8* vbase = (const bf16x8*)V2 + (size_t)b * 65536;
    const __bf16* ktb = kT + (size_t)b * NPIX * CQ_;

    for (int t = 0; t < 8; ++t) {
        int m0 = half * 2048 + t * 256;
        // ---- q-tile A: QK, stats, exp/pack ----
        {
            f32x4 sfr[4];
#pragma unroll
            for (int ms = 0; ms < 4; ++ms) {
                bf16x8 kf;
#pragma unroll
                for (int j = 0; j < 8; ++j) kf[j] = (__bf16)0.f;
                if (g < 2)
                    kf = *(const bf16x8*)&ktb[(size_t)(m0 + w * 64 + ms * 16 + lm) * CQ_ + g * 8];
                f32x4 zz = {0.f, 0.f, 0.f, 0.f};
                sfr[ms] = __builtin_amdgcn_mfma_f32_16x16x32_bf16(kf, qfA, zz, 0, 0, 0);
            }
            float pmax = -1e30f;
#pragma unroll
            for (int ms = 0; ms < 4; ++ms)
#pragma unroll
                for (int r = 0; r < 4; ++r) pmax = fmaxf(pmax, sfr[ms][r]);
            pmax = fmaxf(pmax, __shfl_xor(pmax, 16));
            pmax = fmaxf(pmax, __shfl_xor(pmax, 32));
            if (g == 0) wmaxA[w][lm] = pmax;
            __syncthreads();
            float tmax = fmaxf(fmaxf(wmaxA[0][lm], wmaxA[1][lm]), fmaxf(wmaxA[2][lm], wmaxA[3][lm]));
            float nm = fmaxf(mA, tmax);
            float f = __expf(mA - nm);
            mA = nm;
            if (w == 0 && g == 0) fsA[lm] = f;
            float psum = 0.f;
#pragma unroll
            for (int ms = 0; ms < 4; ++ms) {
                float p0 = __expf(sfr[ms][0] - nm);
                float p1 = __expf(sfr[ms][1] - nm);
                float p2 = __expf(sfr[ms][2] - nm);
                float p3 = __expf(sfr[ms][3] - nm);
                psum += (p0 + p1) + (p2 + p3);
                bf16x4 pk;
                pk[0] = (__bf16)p0; pk[1] = (__bf16)p1; pk[2] = (__bf16)p2; pk[3] = (__bf16)p3;
                *(bf16x4*)&pA[lm * 264 + w * 64 + ms * 16 + g * 4] = pk;
            }
            psum += __shfl_xor(psum, 16);
            psum += __shfl_xor(psum, 32);
            if (g == 0) wsumA[w][lm] = psum;
            __syncthreads();
            float tsum = (wsumA[0][lm] + wsumA[1][lm]) + (wsumA[2][lm] + wsumA[3][lm]);
            lA = lA * f + tsum;
        }
        // ---- q-tile B ----
        {
            f32x4 sfr[4];
#pragma unroll
            for (int ms = 0; ms < 4; ++ms) {
                bf16x8 kf;
#pragma unroll
                for (int j = 0; j < 8; ++j) kf[j] = (__bf16)0.f;
                if (g < 2)
                    kf = *(const bf16x8*)&ktb[(size_t)(m0 + w * 64 + ms * 16 + lm) * CQ_ + g * 8];
                f32x4 zz = {0.f, 0.f, 0.f, 0.f};
                sfr[ms] = __builtin_amdgcn_mfma_f32_16x16x32_bf16(kf, qfB, zz, 0, 0, 0);
            }
            float pmax = -1e30f;
#pragma unroll
            for (int ms = 0; ms < 4; ++ms)
#pragma unroll
                for (int r = 0; r < 4; ++r) pmax = fmaxf(pmax, sfr[ms][r]);
            pmax = fmaxf(pmax, __shfl_xor(pmax, 16));
            pmax = fmaxf(pmax, __shfl_xor(pmax, 32));
            if (g == 0) wmaxB[w][lm] = pmax;
            __syncthreads();
            float tmax = fmaxf(fmaxf(wmaxB[0][lm], wmaxB[1][lm]), fmaxf(wmaxB[2][lm], wmaxB[3][lm]));
            float nm = fmaxf(mB, tmax);
            float f = __expf(mB - nm);
            mB = nm;
            if (w == 0 && g == 0) fsB[lm] = f;
            float psum = 0.f;
#pragma unroll
            for (int ms = 0; ms < 4; ++ms) {
                float p0 = __expf(sfr[ms][0] - nm);
                float p1 = __expf(sfr[ms][1] - nm);
                float p2 = __expf(sfr[ms][2] - nm);
                float p3 = __expf(sfr[ms][3] - nm);
                psum += (p0 + p1) + (p2 + p3);
                bf16x4 pk;
                pk[0] = (__bf16)p0; pk[1] = (__bf16)p1; pk[2] = (__bf16)p2; pk[3] = (__bf16)p3;
                *(bf16x4*)&pB[lm * 264 + w * 64 + ms * 16 + g * 4] = pk;
            }
            psum += __shfl_xor(psum, 16);
            psum += __shfl_xor(psum, 32);
            if (g == 0) wsumB[w][lm] = psum;
            __syncthreads();
            float tsum = (wsumB[0][lm] + wsumB[1][lm]) + (wsumB[2][lm] + wsumB[3][lm]);
            lB = lB * f + tsum;
        }
        // ---- PV: shared V2 loads feed both q-tiles ----
        {
            float fA0 = fsA[g * 4 + 0], fA1 = fsA[g * 4 + 1], fA2 = fsA[g * 4 + 2], fA3 = fsA[g * 4 + 3];
            float fB0 = fsB[g * 4 + 0], fB1 = fsB[g * 4 + 1], fB2 = fsB[g * 4 + 2], fB3 = fsB[g * 4 + 3];
            aA0[0] *= fA0; aA0[1] *= fA1; aA0[2] *= fA2; aA0[3] *= fA3;
            aA1[0] *= fA0; aA1[1] *= fA1; aA1[2] *= fA2; aA1[3] *= fA3;
            aB0[0] *= fB0; aB0[1] *= fB1; aB0[2] *= fB2; aB0[3] *= fB3;
            aB1[0] *= fB0; aB1[1] *= fB1; aB1[2] *= fB2; aB1[3] *= fB3;
#pragma unroll
            for (int ks = 0; ks < 8; ++ks) {
                int msv = (m0 >> 3) + ks * 4 + g;
                bf16x8 bf0 = vbase[msv * 128 + c0];
                bf16x8 bf1 = vbase[msv * 128 + c1];
                bf16x8 afA = *(const bf16x8*)&pA[lm * 264 + ks * 32 + g * 8];
                bf16x8 afB = *(const bf16x8*)&pB[lm * 264 + ks * 32 + g * 8];
                aA0 = __builtin_amdgcn_mfma_f32_16x16x32_bf16(afA, bf0, aA0, 0, 0, 0);
                aA1 = __builtin_amdgcn_mfma_f32_16x16x32_bf16(afA, bf1, aA1, 0, 0, 0);
                aB0 = __builtin_amdgcn_mfma_f32_16x16x32_bf16(afB, bf0, aB0, 0, 0, 0);
                aB1 = __builtin_amdgcn_mfma_f32_16x16x32_bf16(afB, bf1, aB1, 0, 0, 0);
            }
        }
        // pA/pB rewritten only after next tile's first barrier -> safe without a barrier here
    }

    // ---- epilogue: pass A then pass B ----
    __syncthreads();
#pragma unroll
    for (int r = 0; r < 4; ++r) {
        int qrow = g * 4 + r;
        o_lds[c0 * 17 + qrow] = aA0[r];
        o_lds[c1 * 17 + qrow] = aA1[r];
    }
    if (w == 0 && g == 0)
        ml[(size_t)(half * 4 + b) * NPIX + q0 + lm] = make_float2(mA, lA);
    __syncthreads();
    {
        int qi = tid & 15;
        float inv = 1.f / lA;
#pragma unroll
        for (int j = 0; j < 8; ++j) {
            int cc = (tid >> 4) + 16 * j;
            size_t idx = ((size_t)(half * 4 + b) * CO_ + cc) * NPIX + q0 + qi;
            o_part[idx] = (__bf16)(o_lds[cc * 17 + qi] * inv);
        }
    }
    __syncthreads();
#pragma unroll
    for (int r = 0; r < 4; ++r) {
        int qrow = g * 4 + r;
        o_lds[c0 * 17 + qrow] = aB0[r];
        o_lds[c1 * 17 + qrow] = aB1[r];
    }
    if (w == 0 && g == 0)
        ml[(size_t)(half * 4 + b) * NPIX + q0 + 16 + lm] = make_float2(mB, lB);
    __syncthreads();
    {
        int qi = tid & 15;
        float inv = 1.f / lB;
#pragma unroll
        for (int j = 0; j < 8; ++j) {
            int cc = (tid >> 4) + 16 * j;
            size_t idx = ((size_t)(half * 4 + b) * CO_ + cc) * NPIX + q0 + 16 + qi;
            o_part[idx] = (__bf16)(o_lds[cc * 17 + qi] * inv);
        }
    }
}

// combine two KV halves: attn = gam * merged_o + a
__global__ __launch_bounds__(256) void z_acomb(
    const __bf16* __restrict__ o_part, const float2* __restrict__ ml,
    const float* __restrict__ a, const float* __restrict__ gamp, float* __restrict__ attn)
{
    int i = blockIdx.x * 256 + threadIdx.x;   // B*CO*1024
    int n4 = (i & 1023) * 4;
    int co = (i >> 10) & (CO_ - 1);
    int b = i >> 17;
    float gam = gamp[0];
    bf16x4 o1 = *(const bf16x4*)&o_part[((size_t)b * CO_ + co) * NPIX + n4];
    bf16x4 o2 = *(const bf16x4*)&o_part[((size_t)(4 + b) * CO_ + co) * NPIX + n4];
    float4 av = *(const float4*)(a + ((size_t)b * CO_ + co) * NPIX + n4);
    float r[4], ai[4] = {av.x, av.y, av.z, av.w};
#pragma unroll
    for (int e = 0; e < 4; ++e) {
        float2 m1 = ml[(size_t)b * NPIX + n4 + e];
        float2 m2 = ml[(size_t)(4 + b) * NPIX + n4 + e];
        float mm = fmaxf(m1.x, m2.x);
        float w1 = m1.y * __expf(m1.x - mm);
        float w2 = m2.y * __expf(m2.x - mm);
        float o = ((float)o1[e] * w1 + (float)o2[e] * w2) / (w1 + w2);
        r[e] = gam * o + ai[e];
    }
    float4 rv = {r[0], r[1], r[2], r[3]};
    *(float4*)(attn + ((size_t)b * CO_ + co) * NPIX + n4) = rv;
}

// fused gate + final, MFMA everywhere (validated)
__global__ __launch_bounds__(256) void z_fuseout2(
    const float* __restrict__ local, const float* __restrict__ attn, const float* __restrict__ x,
    const __bf16* __restrict__ Wb,
    const float* __restrict__ bg, const float* __restrict__ g3, const float* __restrict__ b3n,
    const float* __restrict__ m3, const float* __restrict__ v3,
    const float* __restrict__ bfb, const float* __restrict__ g4, const float* __restrict__ b4,
    const float* __restrict__ m4, const float* __restrict__ v4,
    const float* __restrict__ rsp, float* __restrict__ out)
{
    __shared__ __align__(16) unsigned char smem[32768 + 4096];
    __bf16* sb2 = (__bf16*)smem;
    __bf16* sxT = (__bf16*)(smem + 28672);

    int tid = threadIdx.x;
    int b = blockIdx.x >> 7;
    int n0 = (blockIdx.x & 127) * 32;

#pragma unroll
    for (int p = 0; p < 4; ++p) {
        int idx = p * 256 + tid;
        int c = idx >> 3, j = idx & 7;
        float lv[4], av[4];
        *(float4*)lv = *(const float4*)(local + ((size_t)b * CO_ + c) * NPIX + n0 + j * 4);
        *(float4*)av = *(const float4*)(attn + ((size_t)b * CO_ + c) * NPIX + n0 + j * 4);
#pragma unroll
        for (int e = 0; e < 4; ++e) {
            int n = j * 4 + e;
            int k1 = 128 + c, k2 = 256 + c;
            sb2[n * 448 + (((k1 >> 3) ^ (n & 7)) << 3) + (k1 & 7)] = (__bf16)lv[e];
            sb2[n * 448 + (((k2 >> 3) ^ (n & 7)) << 3) + (k2 & 7)] = (__bf16)av[e];
        }
    }
#pragma unroll
    for (int p = 0; p < 2; ++p) {
        int idx = p * 256 + tid;
        int c = idx >> 3, j = idx & 7;
        float xv[4];
        *(float4*)xv = *(const float4*)(x + ((size_t)b * CI_ + c) * NPIX + n0 + j * 4);
#pragma unroll
        for (int e = 0; e < 4; ++e) {
            int n = j * 4 + e;
            sxT[n * 64 + (((c >> 3) ^ (n & 7)) << 3) + (c & 7)] = (__bf16)xv[e];
        }
    }
    __syncthreads();

    int l = tid & 63, w = tid >> 6;
    int lm = l & 15, g = l >> 4;
    int co0 = w * 32;
    int t7 = lm & 7;

    f32x4 p1[2][2];
#pragma unroll
    for (int cs = 0; cs < 2; ++cs) {
        float bv = bg[co0 + cs * 16 + lm];
#pragma unroll
        for (int ns = 0; ns < 2; ++ns) {
            p1[ns][cs][0] = bv; p1[ns][cs][1] = bv; p1[ns][cs][2] = bv; p1[ns][cs][3] = bv;
        }
    }
    const __bf16* Wg2 = Wb;
#pragma unroll
    for (int kc = 0; kc < 8; ++kc) {
        int ch = (16 + kc * 4 + g) ^ t7;
        bf16x8 a0 = *(const bf16x8*)&sb2[lm * 448 + ch * 8];
        bf16x8 a1 = *(const bf16x8*)&sb2[(16 + lm) * 448 + ch * 8];
        bf16x8 b0 = *(const bf16x8*)&Wg2[(size_t)(co0 + lm) * 256 + kc * 32 + g * 8];
        bf16x8 b1 = *(const bf16x8*)&Wg2[(size_t)(co0 + 16 + lm) * 256 + kc * 32 + g * 8];
        p1[0][0] = __builtin_amdgcn_mfma_f32_16x16x32_bf16(a0, b0, p1[0][0], 0, 0, 0);
        p1[0][1] = __builtin_amdgcn_mfma_f32_16x16x32_bf16(a0, b1, p1[0][1], 0, 0, 0);
        p1[1][0] = __builtin_amdgcn_mfma_f32_16x16x32_bf16(a1, b0, p1[1][0], 0, 0, 0);
        p1[1][1] = __builtin_amdgcn_mfma_f32_16x16x32_bf16(a1, b1, p1[1][1], 0, 0, 0);
    }
#pragma unroll
    for (int cs = 0; cs < 2; ++cs) {
        int co = co0 + cs * 16 + lm;
        float sc3 = rsqrtf(v3[co] + EPS_) * g3[co];
        float sh3 = b3n[co] - m3[co] * sc3;
        int kl = 128 + co, ka = 256 + co;
#pragma unroll
        for (int ns = 0; ns < 2; ++ns)
#pragma unroll
            for (int r = 0; r < 4; ++r) {
                int n = ns * 16 + g * 4 + r;
                float z = p1[ns][cs][r] * sc3 + sh3;
                float gate = 1.f / (1.f + __expf(-z));
                float lv = (float)sb2[n * 448 + (((kl >> 3) ^ (n & 7)) << 3) + (kl & 7)];
                float av = (float)sb2[n * 448 + (((ka >> 3) ^ (n & 7)) << 3) + (ka & 7)];
                float fu = gate * lv + (1.f - gate) * av;
                sb2[n * 448 + (((co >> 3) ^ (n & 7)) << 3) + (co & 7)] = (__bf16)fu;
            }
    }
    __syncthreads();

    f32x4 p2[2][2], pr[2][2];
#pragma unroll
    for (int cs = 0; cs < 2; ++cs) {
        float bv = bfb[co0 + cs * 16 + lm];
#pragma unroll
        for (int ns = 0; ns < 2; ++ns) {
            p2[ns][cs][0] = bv; p2[ns][cs][1] = bv; p2[ns][cs][2] = bv; p2[ns][cs][3] = bv;
            pr[ns][cs] = (f32x4){0.f, 0.f, 0.f, 0.f};
        }
    }
    const __bf16* Wf2 = Wb + 32768;
    const __bf16* Wr2 = Wb + 81920;
#pragma unroll
    for (int kc = 0; kc < 12; ++kc) {
        int ch = (kc * 4 + g) ^ t7;
        bf16x8 a0 = *(const bf16x8*)&sb2[lm * 448 + ch * 8];
        bf16x8 a1 = *(const bf16x8*)&sb2[(16 + lm) * 448 + ch * 8];
        bf16x8 b0 = *(const bf16x8*)&Wf2[(size_t)(co0 + lm) * 384 + kc * 32 + g * 8];
        bf16x8 b1 = *(const bf16x8*)&Wf2[(size_t)(co0 + 16 + lm) * 384 + kc * 32 + g * 8];
        p2[0][0] = __builtin_amdgcn_mfma_f32_16x16x32_bf16(a0, b0, p2[0][0], 0, 0, 0);
        p2[0][1] = __builtin_amdgcn_mfma_f32_16x16x32_bf16(a0, b1, p2[0][1], 0, 0, 0);
        p2[1][0] = __builtin_amdgcn_mfma_f32_16x16x32_bf16(a1, b0, p2[1][0], 0, 0, 0);
        p2[1][1] = __builtin_amdgcn_mfma_f32_16x16x32_bf16(a1, b1, p2[1][1], 0, 0, 0);
    }
#pragma unroll
    for (int kc = 0; kc < 2; ++kc) {
        int ch = (kc * 4 + g) ^ t7;
        bf16x8 a0 = *(const bf16x8*)&sxT[lm * 64 + ch * 8];
        bf16x8 a1 = *(const bf16x8*)&sxT[(16 + lm) * 64 + ch * 8];
        bf16x8 b0 = *(const bf16x8*)&Wr2[(size_t)(co0 + lm) * 64 + kc * 32 + g * 8];
        bf16x8 b1 = *(const bf16x8*)&Wr2[(size_t)(co0 + 16 + lm) * 64 + kc * 32 + g * 8];
        pr[0][0] = __builtin_amdgcn_mfma_f32_16x16x32_bf16(a0, b0, pr[0][0], 0, 0, 0);
        pr[0][1] = __builtin_amdgcn_mfma_f32_16x16x32_bf16(a0, b1, pr[0][1], 0, 0, 0);
        pr[1][0] = __builtin_amdgcn_mfma_f32_16x16x32_bf16(a1, b0, pr[1][0], 0, 0, 0);
        pr[1][1] = __builtin_amdgcn_mfma_f32_16x16x32_bf16(a1, b1, pr[1][1], 0, 0, 0);
    }
    __syncthreads();

    float* o_lds = (float*)smem;   // [128][36]
    float rsv = rsp[0];
#pragma unroll
    for (int cs = 0; cs < 2; ++cs) {
        int co = co0 + cs * 16 + lm;
        float sc4 = rsqrtf(v4[co] + EPS_) * g4[co];
        float sh4 = b4[co] - m4[co] * sc4;
#pragma unroll
        for (int ns = 0; ns < 2; ++ns)
#pragma unroll
            for (int r = 0; r < 4; ++r) {
                int n = ns * 16 + g * 4 + r;
                float o = fmaxf(p2[ns][cs][r] * sc4 + sh4, 0.f) + rsv * pr[ns][cs][r];
                o_lds[co * 36 + n] = o;
            }
    }
    __syncthreads();
    {
        int c = tid >> 1, h = tid & 1;
#pragma unroll
        for (int j2 = 0; j2 < 4; ++j2) {
            float4 vv = *(float4*)&o_lds[c * 36 + h * 16 + j2 * 4];
            *(float4*)(out + ((size_t)b * CO_ + c) * NPIX + n0 + h * 16 + j2 * 4) = vv;
        }
    }
}

extern "C" void kernel_launch(void* const* d_in, const int* in_sizes, int n_in,
                              void* d_out, int out_size, void* d_ws, size_t ws_size,
                              hipStream_t stream) {
    const float* x   = (const float*)d_in[0];
    const float* W3  = (const float*)d_in[1];
    const float* b3  = (const float*)d_in[2];
    const float* g1  = (const float*)d_in[3];
    const float* b1  = (const float*)d_in[4];
    const float* m1  = (const float*)d_in[5];
    const float* v1  = (const float*)d_in[6];
    const float* Wa  = (const float*)d_in[7];
    const float* ba  = (const float*)d_in[8];
    const float* g2  = (const float*)d_in[9];
    const float* b2  = (const float*)d_in[10];
    const float* m2  = (const float*)d_in[11];
    const float* v2  = (const float*)d_in[12];
    const float* Wq  = (const float*)d_in[13];
    const float* bq  = (const float*)d_in[14];
    const float* Wk  = (const float*)d_in[15];
    const float* bk  = (const float*)d_in[16];
    const float* Wv  = (const float*)d_in[17];
    const float* bv  = (const float*)d_in[18];
    const float* gam = (const float*)d_in[19];
    const float* Wg  = (const float*)d_in[20];
    const float* bg  = (const float*)d_in[21];
    const float* g3  = (const float*)d_in[22];
    const float* b3n = (const float*)d_in[23];
    const float* m3  = (const float*)d_in[24];
    const float* v3  = (const float*)d_in[25];
    const float* Wf  = (const float*)d_in[26];
    const float* bfb = (const float*)d_in[27];
    const float* g4  = (const float*)d_in[28];
    const float* b4  = (const float*)d_in[29];
    const float* m4  = (const float*)d_in[30];
    const float* v4  = (const float*)d_in[31];
    const float* Wr  = (const float*)d_in[32];
    const float* rs  = (const float*)d_in[33];

    float* ws    = (float*)d_ws;
    float* a_    = ws;                       // [0, 2M)
    float* local = ws + 2097152;             // [2M, 4M)
    float* attn  = ws + 4194304;             // [4M, 6M)
    __bf16* V2   = (__bf16*)(ws + 6291456);  // 4 MB bf16
    float* q     = ws + 7340032;             // 262,144 floats
    __bf16* kT   = (__bf16*)(ws + 7602176);  // 512 KB bf16
    __bf16* xT   = (__bf16*)(ws + 7864320);  // 2 MB bf16
    __bf16* Wt2  = (__bf16*)(ws + 8388608);  // 147 KB bf16
    __bf16* Wb   = (__bf16*)(ws + 8450048);  // 232 KB bf16
    __bf16* o_part = (__bf16*)(ws + 8509440);  // 8 MB
    float2* ml   = (float2*)(ws + 10606592);   // 256 KB

    float* out = (float*)d_out;

    z_prepx<<<256, 256, 0, stream>>>(x, xT);
    z_prepw2<<<464, 256, 0, stream>>>(W3, Wt2, Wg, Wf, Wr, Wa, Wq, Wk, Wv, Wb);
    z_mega<<<1024, 256, 0, stream>>>(xT, Wb, ba, g2, b2, m2, v2, bq, bk, bv, a_, q, kT, V2);
    z_attn8<<<1024, 256, 0, stream>>>(q, kT, V2, o_part, ml);
    z_acomb<<<2048, 256, 0, stream>>>(o_part, ml, a_, gam, attn);
    z_conv3m<<<1024, 256, 0, stream>>>(xT, Wt2, b3, g1, b1, m1, v1, local);
    z_fuseout2<<<512, 256, 0, stream>>>(local, attn, x, Wb, bg, g3, b3n, m3, v3,
                                        bfb, g4, b4, m4, v4, rs, out);
}

// Round 19
// 109.602 us; speedup vs baseline: 1.1181x; 1.0296x over previous
//
#include <hip/hip_runtime.h>
#include <hip/hip_bf16.h>

#define CI_ 64
#define CO_ 128
#define NPIX 4096
#define CQ_ 16
#define EPS_ 1e-5f

typedef __attribute__((ext_vector_type(8))) __bf16 bf16x8;
typedef __attribute__((ext_vector_type(4))) __bf16 bf16x4;
typedef __attribute__((ext_vector_type(4))) float f32x4;

// transpose x -> xT[b][n][ci] bf16
__global__ __launch_bounds__(256) void z_prepx(
    const float* __restrict__ x, __bf16* __restrict__ xT)
{
    __shared__ float tl[64][65];
    int b = blockIdx.x >> 6;
    int n0 = (blockIdx.x & 63) * 64;
    int tid = threadIdx.x;
    int nn = tid & 63, c4 = tid >> 6;
#pragma unroll
    for (int p = 0; p < 16; ++p) {
        int ci = p * 4 + c4;
        tl[ci][nn] = x[((size_t)b * CI_ + ci) * NPIX + n0 + nn];
    }
    __syncthreads();
#pragma unroll
    for (int p = 0; p < 2; ++p) {
        int idx = p * 256 + tid;
        int n = idx >> 3, cig = idx & 7;
        bf16x8 vv;
#pragma unroll
        for (int j = 0; j < 8; ++j) vv[j] = (__bf16)tl[cig * 8 + j][n];
        ((bf16x8*)xT)[((size_t)b * NPIX + n0 + n) * 8 + cig] = vv;
    }
}

// fused weight prep: W3 -> Wt2 (73728), and Wg|Wf|Wr|Wa|Wq|Wk|Wv -> Wb (118784)
__global__ __launch_bounds__(256) void z_prepw2(
    const float* __restrict__ W3, __bf16* __restrict__ Wt2,
    const float* __restrict__ Wg, const float* __restrict__ Wf, const float* __restrict__ Wr,
    const float* __restrict__ Wa, const float* __restrict__ Wq, const float* __restrict__ Wk,
    const float* __restrict__ Wv, __bf16* __restrict__ Wb)
{
    int i = blockIdx.x * 256 + threadIdx.x;
    if (i < 73728) {
        int co = i / 576;
        int r = i - co * 576;
        int tap = r >> 6;
        int ci = r & 63;
        Wt2[i] = (__bf16)W3[((size_t)co * CI_ + ci) * 9 + tap];
    }
    if (i < 118784) {
        float val;
        if (i < 32768) val = Wg[i];
        else if (i < 81920) val = Wf[i - 32768];
        else if (i < 90112) val = Wr[i - 81920];
        else if (i < 98304) val = Wa[i - 90112];
        else if (i < 100352) val = Wq[i - 98304];
        else if (i < 102400) val = Wk[i - 100352];
        else val = Wv[i - 102400];
        Wb[i] = (__bf16)val;
    }
}

// fused producer: a = relu(bn2(Wa@x)), then q/kT/V2 from a. All MFMA. (validated)
__global__ __launch_bounds__(256) void z_mega(
    const __bf16* __restrict__ xT, const __bf16* __restrict__ Wb,
    const float* __restrict__ ba, const float* __restrict__ g2, const float* __restrict__ b2,
    const float* __restrict__ m2, const float* __restrict__ v2,
    const float* __restrict__ bq, const float* __restrict__ bk, const float* __restrict__ bv,
    float* __restrict__ a, float* __restrict__ q, __bf16* __restrict__ kT, __bf16* __restrict__ V2)
{
    __shared__ __align__(16) __bf16 an[16 * 128];
    int tid = threadIdx.x;
    int b = blockIdx.x >> 8;
    int n0 = (blockIdx.x & 255) * 16;
    int l = tid & 63, w = tid >> 6;
    int lm = l & 15, g = l >> 4;

    const __bf16* Wa2 = Wb + 90112;
    const __bf16* Wq2 = Wb + 98304;
    const __bf16* Wk2 = Wb + 100352;
    const __bf16* Wv2 = Wb + 102400;

    bf16x8 bx[2];
#pragma unroll
    for (int kc = 0; kc < 2; ++kc)
        bx[kc] = ((const bf16x8*)xT)[((size_t)b * NPIX + n0 + lm) * 8 + (kc * 4 + g)];
    f32x4 pa[2];
#pragma unroll
    for (int ct = 0; ct < 2; ++ct) {
#pragma unroll
        for (int r = 0; r < 4; ++r) pa[ct][r] = ba[w * 32 + ct * 16 + g * 4 + r];
#pragma unroll
        for (int kc = 0; kc < 2; ++kc) {
            bf16x8 afr = *(const bf16x8*)&Wa2[(size_t)(w * 32 + ct * 16 + lm) * 64 + kc * 32 + g * 8];
            pa[ct] = __builtin_amdgcn_mfma_f32_16x16x32_bf16(afr, bx[kc], pa[ct], 0, 0, 0);
        }
    }
#pragma unroll
    for (int ct = 0; ct < 2; ++ct) {
        bf16x4 pk;
#pragma unroll
        for (int r = 0; r < 4; ++r) {
            int co = w * 32 + ct * 16 + g * 4 + r;
            float sc = rsqrtf(v2[co] + EPS_) * g2[co];
            float sh = b2[co] - m2[co] * sc;
            float y = fmaxf(pa[ct][r] * sc + sh, 0.f);
            a[((size_t)b * CO_ + co) * NPIX + n0 + lm] = y;
            pk[r] = (__bf16)y;
        }
        int co8 = w * 4 + ct * 2 + (g >> 1);
        int ch = co8 ^ (lm & 7);
        *(bf16x4*)&an[lm * 128 + ch * 8 + (g & 1) * 4] = pk;
    }
    __syncthreads();

    bf16x8 bn[4];
#pragma unroll
    for (int kc = 0; kc < 4; ++kc) {
        int ch = (kc * 4 + g) ^ (lm & 7);
        bn[kc] = *(const bf16x8*)&an[lm * 128 + ch * 8];
    }
    f32x4 pv[2];
#pragma unroll
    for (int ct = 0; ct < 2; ++ct) {
#pragma unroll
        for (int r = 0; r < 4; ++r) pv[ct][r] = bv[w * 32 + ct * 16 + g * 4 + r];
#pragma unroll
        for (int kc = 0; kc < 4; ++kc) {
            bf16x8 afr = *(const bf16x8*)&Wv2[(size_t)(w * 32 + ct * 16 + lm) * 128 + kc * 32 + g * 8];
            pv[ct] = __builtin_amdgcn_mfma_f32_16x16x32_bf16(afr, bn[kc], pv[ct], 0, 0, 0);
        }
    }
    int n = n0 + lm;
#pragma unroll
    for (int ct = 0; ct < 2; ++ct)
#pragma unroll
        for (int r = 0; r < 4; ++r) {
            int c = w * 32 + ct * 16 + g * 4 + r;
            V2[(size_t)b * 524288 + (size_t)(n >> 3) * 1024 + c * 8 + (n & 7)] = (__bf16)pv[ct][r];
        }
    if (w == 0) {
        f32x4 pq;
#pragma unroll
        for (int r = 0; r < 4; ++r) pq[r] = bq[g * 4 + r];
#pragma unroll
        for (int kc = 0; kc < 4; ++kc) {
            bf16x8 afr = *(const bf16x8*)&Wq2[(size_t)lm * 128 + kc * 32 + g * 8];
            pq = __builtin_amdgcn_mfma_f32_16x16x32_bf16(afr, bn[kc], pq, 0, 0, 0);
        }
#pragma unroll
        for (int r = 0; r < 4; ++r)
            q[((size_t)b * CQ_ + g * 4 + r) * NPIX + n] = pq[r];
    } else if (w == 1) {
        f32x4 pk2;
#pragma unroll
        for (int r = 0; r < 4; ++r) pk2[r] = bk[g * 4 + r];
#pragma unroll
        for (int kc = 0; kc < 4; ++kc) {
            bf16x8 afr = *(const bf16x8*)&Wk2[(size_t)lm * 128 + kc * 32 + g * 8];
            pk2 = __builtin_amdgcn_mfma_f32_16x16x32_bf16(afr, bn[kc], pk2, 0, 0, 0);
        }
        bf16x4 kk;
#pragma unroll
        for (int r = 0; r < 4; ++r) kk[r] = (__bf16)pk2[r];
        *(bf16x4*)&kT[((size_t)b * NPIX + n) * CQ_ + g * 4] = kk;
    }
}

// MFMA implicit-GEMM conv3x3 + BN + ReLU, bf16 output (consumers read via bf16 anyway)
__global__ __launch_bounds__(256) void z_conv3mb(
    const __bf16* __restrict__ xT, const __bf16* __restrict__ Wt2,
    const float* __restrict__ b3, const float* __restrict__ g,
    const float* __restrict__ bb, const float* __restrict__ m,
    const float* __restrict__ v, __bf16* __restrict__ local_bf)
{
    __shared__ __align__(16) __bf16 xt[3 * 66 * 64];
    __shared__ __align__(16) __bf16 wt[32 * 576];
    __shared__ float scs[32], shs[32];

    int blk = blockIdx.x;
    int b = blk >> 8;
    int h = (blk >> 2) & 63;
    int cg = blk & 3;
    int co0 = cg * 32;
    int tid = threadIdx.x;
    int l = tid & 63;
    int nt = tid >> 6;
    int lm = l & 15, lh = l >> 4;

    if (tid < 32) {
        int co = co0 + tid;
        float scv = rsqrtf(v[co] + EPS_) * g[co];
        scs[tid] = scv;
        shs[tid] = (b3[co] - m[co]) * scv + bb[co];
    }

    const bf16x8* xs = (const bf16x8*)xT + (size_t)b * (NPIX * 8);
    for (int i = tid; i < 1584; i += 256) {
        int r = i / 528;
        int rem = i - r * 528;
        int c = rem >> 3;
        int cig = rem & 7;
        int hh = h + r - 1;
        int gc = c - 1;
        bf16x8 val;
#pragma unroll
        for (int j = 0; j < 8; ++j) val[j] = (__bf16)0.f;
        if ((unsigned)hh < 64u && (unsigned)gc < 64u)
            val = xs[(hh * 64 + gc) * 8 + cig];
        *(bf16x8*)&xt[(r * 66 + c) * 64 + ((cig ^ (c & 7)) * 8)] = val;
    }
    const bf16x8* wsrc = (const bf16x8*)Wt2 + (size_t)co0 * 72;
    for (int i = tid; i < 2304; i += 256) {
        int co = i / 72;
        int kc = i - co * 72;
        *(bf16x8*)&wt[co * 576 + ((kc ^ (co & 7)) * 8)] = wsrc[i];
    }
    __syncthreads();

    f32x4 acc0 = {0.f, 0.f, 0.f, 0.f};
    f32x4 acc1 = {0.f, 0.f, 0.f, 0.f};
#pragma unroll
    for (int tap = 0; tap < 9; ++tap) {
        int dh = tap / 3, dw = tap % 3;
#pragma unroll
        for (int ks = 0; ks < 2; ++ks) {
            int cig = ks * 4 + lh;
            int col = nt * 16 + lm + dw;
            bf16x8 bfr = *(const bf16x8*)&xt[(dh * 66 + col) * 64 + ((cig ^ (col & 7)) * 8)];
            int kcg = tap * 8 + cig;
            bf16x8 a0 = *(const bf16x8*)&wt[lm * 576 + ((kcg ^ (lm & 7)) * 8)];
            bf16x8 a1 = *(const bf16x8*)&wt[(16 + lm) * 576 + ((kcg ^ (lm & 7)) * 8)];
            acc0 = __builtin_amdgcn_mfma_f32_16x16x32_bf16(a0, bfr, acc0, 0, 0, 0);
            acc1 = __builtin_amdgcn_mfma_f32_16x16x32_bf16(a1, bfr, acc1, 0, 0, 0);
        }
    }

    size_t obase = (size_t)b * CO_ * NPIX + h * 64 + nt * 16 + lm;
#pragma unroll
    for (int r = 0; r < 4; ++r) {
        int cl0 = lh * 4 + r;
        float y0 = fmaxf(acc0[r] * scs[cl0] + shs[cl0], 0.f);
        local_bf[obase + (size_t)(co0 + cl0) * NPIX] = (__bf16)y0;
        int cl1 = 16 + cl0;
        float y1 = fmaxf(acc1[r] * scs[cl1] + shs[cl1], 0.f);
        local_bf[obase + (size_t)(co0 + cl1) * NPIX] = (__bf16)y1;
    }
}

// QT=32 split-KV MFMA flash attention (validated r18)
__global__ __launch_bounds__(256) void z_attn8(
    const float* __restrict__ q, const __bf16* __restrict__ kT, const __bf16* __restrict__ V2,
    __bf16* __restrict__ o_part, float2* __restrict__ ml)
{
    __shared__ __align__(16) unsigned char smem[16896];
    __shared__ float wmaxA[4][16], wsumA[4][16], fsA[16];
    __shared__ float wmaxB[4][16], wsumB[4][16], fsB[16];
    __bf16* pA = (__bf16*)smem;
    __bf16* pB = (__bf16*)(smem + 8448);
    float* o_lds = (float*)smem;

    int tid = threadIdx.x;
    int b = blockIdx.x >> 8;
    int half = (blockIdx.x >> 7) & 1;
    int q0 = (blockIdx.x & 127) * 32;
    int l = tid & 63;
    int w = tid >> 6;
    int lm = l & 15;
    int g = l >> 4;

    bf16x8 qfA, qfB;
#pragma unroll
    for (int j = 0; j < 8; ++j) { qfA[j] = (__bf16)0.f; qfB[j] = (__bf16)0.f; }
    if (g < 2) {
#pragma unroll
        for (int j = 0; j < 8; ++j) {
            qfA[j] = (__bf16)q[((size_t)b * CQ_ + g * 8 + j) * NPIX + q0 + lm];
            qfB[j] = (__bf16)q[((size_t)b * CQ_ + g * 8 + j) * NPIX + q0 + 16 + lm];
        }
    }

    float mA = -1e30f, lA = 0.f, mB = -1e30f, lB = 0.f;
    f32x4 aA0 = {0.f,0.f,0.f,0.f}, aA1 = {0.f,0.f,0.f,0.f};
    f32x4 aB0 = {0.f,0.f,0.f,0.f}, aB1 = {0.f,0.f,0.f,0.f};
    int c0 = w * 32 + lm;
    int c1 = c0 + 16;
    const bf16x8* vbase = (const bf16x8*)V2 + (size_t)b * 65536;
    const __bf16* ktb = kT + (size_t)b * NPIX * CQ_;

    for (int t = 0; t < 8; ++t) {
        int m0 = half * 2048 + t * 256;
        {
            f32x4 sfr[4];
#pragma unroll
            for (int ms = 0; ms < 4; ++ms) {
                bf16x8 kf;
#pragma unroll
                for (int j = 0; j < 8; ++j) kf[j] = (__bf16)0.f;
                if (g < 2)
                    kf = *(const bf16x8*)&ktb[(size_t)(m0 + w * 64 + ms * 16 + lm) * CQ_ + g * 8];
                f32x4 zz = {0.f, 0.f, 0.f, 0.f};
                sfr[ms] = __builtin_amdgcn_mfma_f32_16x16x32_bf16(kf, qfA, zz, 0, 0, 0);
            }
            float pmax = -1e30f;
#pragma unroll
            for (int ms = 0; ms < 4; ++ms)
#pragma unroll
                for (int r = 0; r < 4; ++r) pmax = fmaxf(pmax, sfr[ms][r]);
            pmax = fmaxf(pmax, __shfl_xor(pmax, 16));
            pmax = fmaxf(pmax, __shfl_xor(pmax, 32));
            if (g == 0) wmaxA[w][lm] = pmax;
            __syncthreads();
            float tmax = fmaxf(fmaxf(wmaxA[0][lm], wmaxA[1][lm]), fmaxf(wmaxA[2][lm], wmaxA[3][lm]));
            float nm = fmaxf(mA, tmax);
            float f = __expf(mA - nm);
            mA = nm;
            if (w == 0 && g == 0) fsA[lm] = f;
            float psum = 0.f;
#pragma unroll
            for (int ms = 0; ms < 4; ++ms) {
                float p0 = __expf(sfr[ms][0] - nm);
                float p1 = __expf(sfr[ms][1] - nm);
                float p2 = __expf(sfr[ms][2] - nm);
                float p3 = __expf(sfr[ms][3] - nm);
                psum += (p0 + p1) + (p2 + p3);
                bf16x4 pk;
                pk[0] = (__bf16)p0; pk[1] = (__bf16)p1; pk[2] = (__bf16)p2; pk[3] = (__bf16)p3;
                *(bf16x4*)&pA[lm * 264 + w * 64 + ms * 16 + g * 4] = pk;
            }
            psum += __shfl_xor(psum, 16);
            psum += __shfl_xor(psum, 32);
            if (g == 0) wsumA[w][lm] = psum;
            __syncthreads();
            float tsum = (wsumA[0][lm] + wsumA[1][lm]) + (wsumA[2][lm] + wsumA[3][lm]);
            lA = lA * f + tsum;
        }
        {
            f32x4 sfr[4];
#pragma unroll
            for (int ms = 0; ms < 4; ++ms) {
                bf16x8 kf;
#pragma unroll
                for (int j = 0; j < 8; ++j) kf[j] = (__bf16)0.f;
                if (g < 2)
                    kf = *(const bf16x8*)&ktb[(size_t)(m0 + w * 64 + ms * 16 + lm) * CQ_ + g * 8];
                f32x4 zz = {0.f, 0.f, 0.f, 0.f};
                sfr[ms] = __builtin_amdgcn_mfma_f32_16x16x32_bf16(kf, qfB, zz, 0, 0, 0);
            }
            float pmax = -1e30f;
#pragma unroll
            for (int ms = 0; ms < 4; ++ms)
#pragma unroll
                for (int r = 0; r < 4; ++r) pmax = fmaxf(pmax, sfr[ms][r]);
            pmax = fmaxf(pmax, __shfl_xor(pmax, 16));
            pmax = fmaxf(pmax, __shfl_xor(pmax, 32));
            if (g == 0) wmaxB[w][lm] = pmax;
            __syncthreads();
            float tmax = fmaxf(fmaxf(wmaxB[0][lm], wmaxB[1][lm]), fmaxf(wmaxB[2][lm], wmaxB[3][lm]));
            float nm = fmaxf(mB, tmax);
            float f = __expf(mB - nm);
            mB = nm;
            if (w == 0 && g == 0) fsB[lm] = f;
            float psum = 0.f;
#pragma unroll
            for (int ms = 0; ms < 4; ++ms) {
                float p0 = __expf(sfr[ms][0] - nm);
                float p1 = __expf(sfr[ms][1] - nm);
                float p2 = __expf(sfr[ms][2] - nm);
                float p3 = __expf(sfr[ms][3] - nm);
                psum += (p0 + p1) + (p2 + p3);
                bf16x4 pk;
                pk[0] = (__bf16)p0; pk[1] = (__bf16)p1; pk[2] = (__bf16)p2; pk[3] = (__bf16)p3;
                *(bf16x4*)&pB[lm * 264 + w * 64 + ms * 16 + g * 4] = pk;
            }
            psum += __shfl_xor(psum, 16);
            psum += __shfl_xor(psum, 32);
            if (g == 0) wsumB[w][lm] = psum;
            __syncthreads();
            float tsum = (wsumB[0][lm] + wsumB[1][lm]) + (wsumB[2][lm] + wsumB[3][lm]);
            lB = lB * f + tsum;
        }
        {
            float fA0 = fsA[g * 4 + 0], fA1 = fsA[g * 4 + 1], fA2 = fsA[g * 4 + 2], fA3 = fsA[g * 4 + 3];
            float fB0 = fsB[g * 4 + 0], fB1 = fsB[g * 4 + 1], fB2 = fsB[g * 4 + 2], fB3 = fsB[g * 4 + 3];
            aA0[0] *= fA0; aA0[1] *= fA1; aA0[2] *= fA2; aA0[3] *= fA3;
            aA1[0] *= fA0; aA1[1] *= fA1; aA1[2] *= fA2; aA1[3] *= fA3;
            aB0[0] *= fB0; aB0[1] *= fB1; aB0[2] *= fB2; aB0[3] *= fB3;
            aB1[0] *= fB0; aB1[1] *= fB1; aB1[2] *= fB2; aB1[3] *= fB3;
#pragma unroll
            for (int ks = 0; ks < 8; ++ks) {
                int msv = (m0 >> 3) + ks * 4 + g;
                bf16x8 bf0 = vbase[msv * 128 + c0];
                bf16x8 bf1 = vbase[msv * 128 + c1];
                bf16x8 afA = *(const bf16x8*)&pA[lm * 264 + ks * 32 + g * 8];
                bf16x8 afB = *(const bf16x8*)&pB[lm * 264 + ks * 32 + g * 8];
                aA0 = __builtin_amdgcn_mfma_f32_16x16x32_bf16(afA, bf0, aA0, 0, 0, 0);
                aA1 = __builtin_amdgcn_mfma_f32_16x16x32_bf16(afA, bf1, aA1, 0, 0, 0);
                aB0 = __builtin_amdgcn_mfma_f32_16x16x32_bf16(afB, bf0, aB0, 0, 0, 0);
                aB1 = __builtin_amdgcn_mfma_f32_16x16x32_bf16(afB, bf1, aB1, 0, 0, 0);
            }
        }
    }

    __syncthreads();
#pragma unroll
    for (int r = 0; r < 4; ++r) {
        int qrow = g * 4 + r;
        o_lds[c0 * 17 + qrow] = aA0[r];
        o_lds[c1 * 17 + qrow] = aA1[r];
    }
    if (w == 0 && g == 0)
        ml[(size_t)(half * 4 + b) * NPIX + q0 + lm] = make_float2(mA, lA);
    __syncthreads();
    {
        int qi = tid & 15;
        float inv = 1.f / lA;
#pragma unroll
        for (int j = 0; j < 8; ++j) {
            int cc = (tid >> 4) + 16 * j;
            size_t idx = ((size_t)(half * 4 + b) * CO_ + cc) * NPIX + q0 + qi;
            o_part[idx] = (__bf16)(o_lds[cc * 17 + qi] * inv);
        }
    }
    __syncthreads();
#pragma unroll
    for (int r = 0; r < 4; ++r) {
        int qrow = g * 4 + r;
        o_lds[c0 * 17 + qrow] = aB0[r];
        o_lds[c1 * 17 + qrow] = aB1[r];
    }
    if (w == 0 && g == 0)
        ml[(size_t)(half * 4 + b) * NPIX + q0 + 16 + lm] = make_float2(mB, lB);
    __syncthreads();
    {
        int qi = tid & 15;
        float inv = 1.f / lB;
#pragma unroll
        for (int j = 0; j < 8; ++j) {
            int cc = (tid >> 4) + 16 * j;
            size_t idx = ((size_t)(half * 4 + b) * CO_ + cc) * NPIX + q0 + 16 + qi;
            o_part[idx] = (__bf16)(o_lds[cc * 17 + qi] * inv);
        }
    }
}

// fused merge + gate + final. Merges split-KV o_part inline during staging.
__global__ __launch_bounds__(256) void z_fuseout3(
    const __bf16* __restrict__ local_bf, const __bf16* __restrict__ o_part,
    const float2* __restrict__ ml, const float* __restrict__ a,
    const float* __restrict__ gamp, const __bf16* __restrict__ xT,
    const __bf16* __restrict__ Wb,
    const float* __restrict__ bg, const float* __restrict__ g3, const float* __restrict__ b3n,
    const float* __restrict__ m3, const float* __restrict__ v3,
    const float* __restrict__ bfb, const float* __restrict__ g4, const float* __restrict__ b4,
    const float* __restrict__ m4, const float* __restrict__ v4,
    const float* __restrict__ rsp, float* __restrict__ out)
{
    __shared__ __align__(16) unsigned char smem[32768 + 4096];
    __shared__ float wA[32], wB[32];
    __bf16* sb2 = (__bf16*)smem;
    __bf16* sxT = (__bf16*)(smem + 28672);

    int tid = threadIdx.x;
    int b = blockIdx.x >> 7;
    int n0 = (blockIdx.x & 127) * 32;

    // per-n LSE merge weights
    if (tid < 32) {
        float2 m1 = ml[(size_t)b * NPIX + n0 + tid];
        float2 m2 = ml[(size_t)(4 + b) * NPIX + n0 + tid];
        float mm = fmaxf(m1.x, m2.x);
        float w1 = m1.y * __expf(m1.x - mm);
        float w2 = m2.y * __expf(m2.x - mm);
        float inv = 1.f / (w1 + w2);
        wA[tid] = w1 * inv;
        wB[tid] = w2 * inv;
    }
    __syncthreads();

    float gam = gamp[0];
#pragma unroll
    for (int p = 0; p < 4; ++p) {
        int idx = p * 256 + tid;
        int c = idx >> 3, j = idx & 7;
        bf16x4 lv = *(const bf16x4*)&local_bf[((size_t)b * CO_ + c) * NPIX + n0 + j * 4];
        bf16x4 o1 = *(const bf16x4*)&o_part[((size_t)b * CO_ + c) * NPIX + n0 + j * 4];
        bf16x4 o2 = *(const bf16x4*)&o_part[((size_t)(4 + b) * CO_ + c) * NPIX + n0 + j * 4];
        float av[4];
        *(float4*)av = *(const float4*)(a + ((size_t)b * CO_ + c) * NPIX + n0 + j * 4);
#pragma unroll
        for (int e = 0; e < 4; ++e) {
            int n = j * 4 + e;
            int k1 = 128 + c, k2 = 256 + c;
            sb2[n * 448 + (((k1 >> 3) ^ (n & 7)) << 3) + (k1 & 7)] = lv[e];
            float o = (float)o1[e] * wA[n] + (float)o2[e] * wB[n];
            sb2[n * 448 + (((k2 >> 3) ^ (n & 7)) << 3) + (k2 & 7)] = (__bf16)(gam * o + av[e]);
        }
    }
    // x staging straight from bf16 xT (already n-major)
#pragma unroll
    for (int p = 0; p < 2; ++p) {
        int idx = p * 256 + tid;
        int n = idx >> 3, cig = idx & 7;
        bf16x8 vv = ((const bf16x8*)xT)[((size_t)b * NPIX + n0 + n) * 8 + cig];
        *(bf16x8*)&sxT[n * 64 + ((cig ^ (n & 7)) << 3)] = vv;
    }
    __syncthreads();

    int l = tid & 63, w = tid >> 6;
    int lm = l & 15, g = l >> 4;
    int co0 = w * 32;
    int t7 = lm & 7;

    f32x4 p1[2][2];
#pragma unroll
    for (int cs = 0; cs < 2; ++cs) {
        float bv = bg[co0 + cs * 16 + lm];
#pragma unroll
        for (int ns = 0; ns < 2; ++ns) {
            p1[ns][cs][0] = bv; p1[ns][cs][1] = bv; p1[ns][cs][2] = bv; p1[ns][cs][3] = bv;
        }
    }
    const __bf16* Wg2 = Wb;
#pragma unroll
    for (int kc = 0; kc < 8; ++kc) {
        int ch = (16 + kc * 4 + g) ^ t7;
        bf16x8 a0 = *(const bf16x8*)&sb2[lm * 448 + ch * 8];
        bf16x8 a1 = *(const bf16x8*)&sb2[(16 + lm) * 448 + ch * 8];
        bf16x8 b0 = *(const bf16x8*)&Wg2[(size_t)(co0 + lm) * 256 + kc * 32 + g * 8];
        bf16x8 b1 = *(const bf16x8*)&Wg2[(size_t)(co0 + 16 + lm) * 256 + kc * 32 + g * 8];
        p1[0][0] = __builtin_amdgcn_mfma_f32_16x16x32_bf16(a0, b0, p1[0][0], 0, 0, 0);
        p1[0][1] = __builtin_amdgcn_mfma_f32_16x16x32_bf16(a0, b1, p1[0][1], 0, 0, 0);
        p1[1][0] = __builtin_amdgcn_mfma_f32_16x16x32_bf16(a1, b0, p1[1][0], 0, 0, 0);
        p1[1][1] = __builtin_amdgcn_mfma_f32_16x16x32_bf16(a1, b1, p1[1][1], 0, 0, 0);
    }
#pragma unroll
    for (int cs = 0; cs < 2; ++cs) {
        int co = co0 + cs * 16 + lm;
        float sc3 = rsqrtf(v3[co] + EPS_) * g3[co];
        float sh3 = b3n[co] - m3[co] * sc3;
        int kl = 128 + co, ka = 256 + co;
#pragma unroll
        for (int ns = 0; ns < 2; ++ns)
#pragma unroll
            for (int r = 0; r < 4; ++r) {
                int n = ns * 16 + g * 4 + r;
                float z = p1[ns][cs][r] * sc3 + sh3;
                float gate = 1.f / (1.f + __expf(-z));
                float lv = (float)sb2[n * 448 + (((kl >> 3) ^ (n & 7)) << 3) + (kl & 7)];
                float av = (float)sb2[n * 448 + (((ka >> 3) ^ (n & 7)) << 3) + (ka & 7)];
                float fu = gate * lv + (1.f - gate) * av;
                sb2[n * 448 + (((co >> 3) ^ (n & 7)) << 3) + (co & 7)] = (__bf16)fu;
            }
    }
    __syncthreads();

    f32x4 p2[2][2], pr[2][2];
#pragma unroll
    for (int cs = 0; cs < 2; ++cs) {
        float bv = bfb[co0 + cs * 16 + lm];
#pragma unroll
        for (int ns = 0; ns < 2; ++ns) {
            p2[ns][cs][0] = bv; p2[ns][cs][1] = bv; p2[ns][cs][2] = bv; p2[ns][cs][3] = bv;
            pr[ns][cs] = (f32x4){0.f, 0.f, 0.f, 0.f};
        }
    }
    const __bf16* Wf2 = Wb + 32768;
    const __bf16* Wr2 = Wb + 81920;
#pragma unroll
    for (int kc = 0; kc < 12; ++kc) {
        int ch = (kc * 4 + g) ^ t7;
        bf16x8 a0 = *(const bf16x8*)&sb2[lm * 448 + ch * 8];
        bf16x8 a1 = *(const bf16x8*)&sb2[(16 + lm) * 448 + ch * 8];
        bf16x8 b0 = *(const bf16x8*)&Wf2[(size_t)(co0 + lm) * 384 + kc * 32 + g * 8];
        bf16x8 b1 = *(const bf16x8*)&Wf2[(size_t)(co0 + 16 + lm) * 384 + kc * 32 + g * 8];
        p2[0][0] = __builtin_amdgcn_mfma_f32_16x16x32_bf16(a0, b0, p2[0][0], 0, 0, 0);
        p2[0][1] = __builtin_amdgcn_mfma_f32_16x16x32_bf16(a0, b1, p2[0][1], 0, 0, 0);
        p2[1][0] = __builtin_amdgcn_mfma_f32_16x16x32_bf16(a1, b0, p2[1][0], 0, 0, 0);
        p2[1][1] = __builtin_amdgcn_mfma_f32_16x16x32_bf16(a1, b1, p2[1][1], 0, 0, 0);
    }
#pragma unroll
    for (int kc = 0; kc < 2; ++kc) {
        int ch = (kc * 4 + g) ^ t7;
        bf16x8 a0 = *(const bf16x8*)&sxT[lm * 64 + ch * 8];
        bf16x8 a1 = *(const bf16x8*)&sxT[(16 + lm) * 64 + ch * 8];
        bf16x8 b0 = *(const bf16x8*)&Wr2[(size_t)(co0 + lm) * 64 + kc * 32 + g * 8];
        bf16x8 b1 = *(const bf16x8*)&Wr2[(size_t)(co0 + 16 + lm) * 64 + kc * 32 + g * 8];
        pr[0][0] = __builtin_amdgcn_mfma_f32_16x16x32_bf16(a0, b0, pr[0][0], 0, 0, 0);
        pr[0][1] = __builtin_amdgcn_mfma_f32_16x16x32_bf16(a0, b1, pr[0][1], 0, 0, 0);
        pr[1][0] = __builtin_amdgcn_mfma_f32_16x16x32_bf16(a1, b0, pr[1][0], 0, 0, 0);
        pr[1][1] = __builtin_amdgcn_mfma_f32_16x16x32_bf16(a1, b1, pr[1][1], 0, 0, 0);
    }
    __syncthreads();

    float* o_lds = (float*)smem;   // [128][36]
    float rsv = rsp[0];
#pragma unroll
    for (int cs = 0; cs < 2; ++cs) {
        int co = co0 + cs * 16 + lm;
        float sc4 = rsqrtf(v4[co] + EPS_) * g4[co];
        float sh4 = b4[co] - m4[co] * sc4;
#pragma unroll
        for (int ns = 0; ns < 2; ++ns)
#pragma unroll
            for (int r = 0; r < 4; ++r) {
                int n = ns * 16 + g * 4 + r;
                float o = fmaxf(p2[ns][cs][r] * sc4 + sh4, 0.f) + rsv * pr[ns][cs][r];
                o_lds[co * 36 + n] = o;
            }
    }
    __syncthreads();
    {
        int c = tid >> 1, h = tid & 1;
#pragma unroll
        for (int j2 = 0; j2 < 4; ++j2) {
            float4 vv = *(float4*)&o_lds[c * 36 + h * 16 + j2 * 4];
            *(float4*)(out + ((size_t)b * CO_ + c) * NPIX + n0 + h * 16 + j2 * 4) = vv;
        }
    }
}

extern "C" void kernel_launch(void* const* d_in, const int* in_sizes, int n_in,
                              void* d_out, int out_size, void* d_ws, size_t ws_size,
                              hipStream_t stream) {
    const float* x   = (const float*)d_in[0];
    const float* W3  = (const float*)d_in[1];
    const float* b3  = (const float*)d_in[2];
    const float* g1  = (const float*)d_in[3];
    const float* b1  = (const float*)d_in[4];
    const float* m1  = (const float*)d_in[5];
    const float* v1  = (const float*)d_in[6];
    const float* Wa  = (const float*)d_in[7];
    const float* ba  = (const float*)d_in[8];
    const float* g2  = (const float*)d_in[9];
    const float* b2  = (const float*)d_in[10];
    const float* m2  = (const float*)d_in[11];
    const float* v2  = (const float*)d_in[12];
    const float* Wq  = (const float*)d_in[13];
    const float* bq  = (const float*)d_in[14];
    const float* Wk  = (const float*)d_in[15];
    const float* bk  = (const float*)d_in[16];
    const float* Wv  = (const float*)d_in[17];
    const float* bv  = (const float*)d_in[18];
    const float* gam = (const float*)d_in[19];
    const float* Wg  = (const float*)d_in[20];
    const float* bg  = (const float*)d_in[21];
    const float* g3  = (const float*)d_in[22];
    const float* b3n = (const float*)d_in[23];
    const float* m3  = (const float*)d_in[24];
    const float* v3  = (const float*)d_in[25];
    const float* Wf  = (const float*)d_in[26];
    const float* bfb = (const float*)d_in[27];
    const float* g4  = (const float*)d_in[28];
    const float* b4  = (const float*)d_in[29];
    const float* m4  = (const float*)d_in[30];
    const float* v4  = (const float*)d_in[31];
    const float* Wr  = (const float*)d_in[32];
    const float* rs  = (const float*)d_in[33];

    float* ws      = (float*)d_ws;
    float* a_      = ws;                         // 8 MB fp32
    __bf16* local_bf = (__bf16*)(ws + 2097152);  // 4 MB bf16
    __bf16* V2     = (__bf16*)(ws + 3145728);    // 4 MB bf16
    float* q       = ws + 4194304;               // 1 MB fp32
    __bf16* kT     = (__bf16*)(ws + 4456448);    // 512 KB bf16
    __bf16* xT     = (__bf16*)(ws + 4587520);    // 2 MB bf16
    __bf16* Wt2    = (__bf16*)(ws + 5111808);    // 147 KB bf16
    __bf16* Wb     = (__bf16*)(ws + 5152768);    // 232 KB bf16
    __bf16* o_part = (__bf16*)(ws + 5214208);    // 8 MB bf16
    float2* ml     = (float2*)(ws + 7311360);    // 512 KB
    // total ≈ 28.5 MB

    float* out = (float*)d_out;

    z_prepx<<<256, 256, 0, stream>>>(x, xT);
    z_prepw2<<<464, 256, 0, stream>>>(W3, Wt2, Wg, Wf, Wr, Wa, Wq, Wk, Wv, Wb);
    z_mega<<<1024, 256, 0, stream>>>(xT, Wb, ba, g2, b2, m2, v2, bq, bk, bv, a_, q, kT, V2);
    z_attn8<<<1024, 256, 0, stream>>>(q, kT, V2, o_part, ml);
    z_conv3mb<<<1024, 256, 0, stream>>>(xT, Wt2, b3, g1, b1, m1, v1, local_bf);
    z_fuseout3<<<512, 256, 0, stream>>>(local_bf, o_part, ml, a_, gam, xT, Wb,
                                        bg, g3, b3n, m3, v3, bfb, g4, b4, m4, v4, rs, out);
}

// Round 20
// 106.546 us; speedup vs baseline: 1.1502x; 1.0287x over previous
//
#include <hip/hip_runtime.h>
#include <hip/hip_bf16.h>

#define CI_ 64
#define CO_ 128
#define NPIX 4096
#define CQ_ 16
#define EPS_ 1e-5f

typedef __attribute__((ext_vector_type(8))) __bf16 bf16x8;
typedef __attribute__((ext_vector_type(4))) __bf16 bf16x4;
typedef __attribute__((ext_vector_type(4))) float f32x4;

// transpose x -> xT[b][n][ci] bf16
__global__ __launch_bounds__(256) void z_prepx(
    const float* __restrict__ x, __bf16* __restrict__ xT)
{
    __shared__ float tl[64][65];
    int b = blockIdx.x >> 6;
    int n0 = (blockIdx.x & 63) * 64;
    int tid = threadIdx.x;
    int nn = tid & 63, c4 = tid >> 6;
#pragma unroll
    for (int p = 0; p < 16; ++p) {
        int ci = p * 4 + c4;
        tl[ci][nn] = x[((size_t)b * CI_ + ci) * NPIX + n0 + nn];
    }
    __syncthreads();
#pragma unroll
    for (int p = 0; p < 2; ++p) {
        int idx = p * 256 + tid;
        int n = idx >> 3, cig = idx & 7;
        bf16x8 vv;
#pragma unroll
        for (int j = 0; j < 8; ++j) vv[j] = (__bf16)tl[cig * 8 + j][n];
        ((bf16x8*)xT)[((size_t)b * NPIX + n0 + n) * 8 + cig] = vv;
    }
}

// fused weight prep
__global__ __launch_bounds__(256) void z_prepw2(
    const float* __restrict__ W3, __bf16* __restrict__ Wt2,
    const float* __restrict__ Wg, const float* __restrict__ Wf, const float* __restrict__ Wr,
    const float* __restrict__ Wa, const float* __restrict__ Wq, const float* __restrict__ Wk,
    const float* __restrict__ Wv, __bf16* __restrict__ Wb)
{
    int i = blockIdx.x * 256 + threadIdx.x;
    if (i < 73728) {
        int co = i / 576;
        int r = i - co * 576;
        int tap = r >> 6;
        int ci = r & 63;
        Wt2[i] = (__bf16)W3[((size_t)co * CI_ + ci) * 9 + tap];
    }
    if (i < 118784) {
        float val;
        if (i < 32768) val = Wg[i];
        else if (i < 81920) val = Wf[i - 32768];
        else if (i < 90112) val = Wr[i - 81920];
        else if (i < 98304) val = Wa[i - 90112];
        else if (i < 100352) val = Wq[i - 98304];
        else if (i < 102400) val = Wk[i - 100352];
        else val = Wv[i - 102400];
        Wb[i] = (__bf16)val;
    }
}

// fused producer: a = relu(bn2(Wa@x)), then qT/kT/V2 from a. All MFMA.
__global__ __launch_bounds__(256) void z_mega(
    const __bf16* __restrict__ xT, const __bf16* __restrict__ Wb,
    const float* __restrict__ ba, const float* __restrict__ g2, const float* __restrict__ b2,
    const float* __restrict__ m2, const float* __restrict__ v2,
    const float* __restrict__ bq, const float* __restrict__ bk, const float* __restrict__ bv,
    float* __restrict__ a, __bf16* __restrict__ qT, __bf16* __restrict__ kT, __bf16* __restrict__ V2)
{
    __shared__ __align__(16) __bf16 an[16 * 128];
    int tid = threadIdx.x;
    int b = blockIdx.x >> 8;
    int n0 = (blockIdx.x & 255) * 16;
    int l = tid & 63, w = tid >> 6;
    int lm = l & 15, g = l >> 4;

    const __bf16* Wa2 = Wb + 90112;
    const __bf16* Wq2 = Wb + 98304;
    const __bf16* Wk2 = Wb + 100352;
    const __bf16* Wv2 = Wb + 102400;

    bf16x8 bx[2];
#pragma unroll
    for (int kc = 0; kc < 2; ++kc)
        bx[kc] = ((const bf16x8*)xT)[((size_t)b * NPIX + n0 + lm) * 8 + (kc * 4 + g)];
    f32x4 pa[2];
#pragma unroll
    for (int ct = 0; ct < 2; ++ct) {
#pragma unroll
        for (int r = 0; r < 4; ++r) pa[ct][r] = ba[w * 32 + ct * 16 + g * 4 + r];
#pragma unroll
        for (int kc = 0; kc < 2; ++kc) {
            bf16x8 afr = *(const bf16x8*)&Wa2[(size_t)(w * 32 + ct * 16 + lm) * 64 + kc * 32 + g * 8];
            pa[ct] = __builtin_amdgcn_mfma_f32_16x16x32_bf16(afr, bx[kc], pa[ct], 0, 0, 0);
        }
    }
#pragma unroll
    for (int ct = 0; ct < 2; ++ct) {
        bf16x4 pk;
#pragma unroll
        for (int r = 0; r < 4; ++r) {
            int co = w * 32 + ct * 16 + g * 4 + r;
            float sc = rsqrtf(v2[co] + EPS_) * g2[co];
            float sh = b2[co] - m2[co] * sc;
            float y = fmaxf(pa[ct][r] * sc + sh, 0.f);
            a[((size_t)b * CO_ + co) * NPIX + n0 + lm] = y;
            pk[r] = (__bf16)y;
        }
        int co8 = w * 4 + ct * 2 + (g >> 1);
        int ch = co8 ^ (lm & 7);
        *(bf16x4*)&an[lm * 128 + ch * 8 + (g & 1) * 4] = pk;
    }
    __syncthreads();

    bf16x8 bn[4];
#pragma unroll
    for (int kc = 0; kc < 4; ++kc) {
        int ch = (kc * 4 + g) ^ (lm & 7);
        bn[kc] = *(const bf16x8*)&an[lm * 128 + ch * 8];
    }
    f32x4 pv[2];
#pragma unroll
    for (int ct = 0; ct < 2; ++ct) {
#pragma unroll
        for (int r = 0; r < 4; ++r) pv[ct][r] = bv[w * 32 + ct * 16 + g * 4 + r];
#pragma unroll
        for (int kc = 0; kc < 4; ++kc) {
            bf16x8 afr = *(const bf16x8*)&Wv2[(size_t)(w * 32 + ct * 16 + lm) * 128 + kc * 32 + g * 8];
            pv[ct] = __builtin_amdgcn_mfma_f32_16x16x32_bf16(afr, bn[kc], pv[ct], 0, 0, 0);
        }
    }
    int n = n0 + lm;
#pragma unroll
    for (int ct = 0; ct < 2; ++ct)
#pragma unroll
        for (int r = 0; r < 4; ++r) {
            int c = w * 32 + ct * 16 + g * 4 + r;
            V2[(size_t)b * 524288 + (size_t)(n >> 3) * 1024 + c * 8 + (n & 7)] = (__bf16)pv[ct][r];
        }
    if (w == 0) {
        f32x4 pq;
#pragma unroll
        for (int r = 0; r < 4; ++r) pq[r] = bq[g * 4 + r];
#pragma unroll
        for (int kc = 0; kc < 4; ++kc) {
            bf16x8 afr = *(const bf16x8*)&Wq2[(size_t)lm * 128 + kc * 32 + g * 8];
            pq = __builtin_amdgcn_mfma_f32_16x16x32_bf16(afr, bn[kc], pq, 0, 0, 0);
        }
        bf16x4 qq;
#pragma unroll
        for (int r = 0; r < 4; ++r) qq[r] = (__bf16)pq[r];
        *(bf16x4*)&qT[((size_t)b * NPIX + n) * CQ_ + g * 4] = qq;
    } else if (w == 1) {
        f32x4 pk2;
#pragma unroll
        for (int r = 0; r < 4; ++r) pk2[r] = bk[g * 4 + r];
#pragma unroll
        for (int kc = 0; kc < 4; ++kc) {
            bf16x8 afr = *(const bf16x8*)&Wk2[(size_t)lm * 128 + kc * 32 + g * 8];
            pk2 = __builtin_amdgcn_mfma_f32_16x16x32_bf16(afr, bn[kc], pk2, 0, 0, 0);
        }
        bf16x4 kk;
#pragma unroll
        for (int r = 0; r < 4; ++r) kk[r] = (__bf16)pk2[r];
        *(bf16x4*)&kT[((size_t)b * NPIX + n) * CQ_ + g * 4] = kk;
    }
}

// MFMA implicit-GEMM conv3x3 + BN + ReLU, bf16 output (validated)
__global__ __launch_bounds__(256) void z_conv3mb(
    const __bf16* __restrict__ xT, const __bf16* __restrict__ Wt2,
    const float* __restrict__ b3, const float* __restrict__ g,
    const float* __restrict__ bb, const float* __restrict__ m,
    const float* __restrict__ v, __bf16* __restrict__ local_bf)
{
    __shared__ __align__(16) __bf16 xt[3 * 66 * 64];
    __shared__ __align__(16) __bf16 wt[32 * 576];
    __shared__ float scs[32], shs[32];

    int blk = blockIdx.x;
    int b = blk >> 8;
    int h = (blk >> 2) & 63;
    int cg = blk & 3;
    int co0 = cg * 32;
    int tid = threadIdx.x;
    int l = tid & 63;
    int nt = tid >> 6;
    int lm = l & 15, lh = l >> 4;

    if (tid < 32) {
        int co = co0 + tid;
        float scv = rsqrtf(v[co] + EPS_) * g[co];
        scs[tid] = scv;
        shs[tid] = (b3[co] - m[co]) * scv + bb[co];
    }

    const bf16x8* xs = (const bf16x8*)xT + (size_t)b * (NPIX * 8);
    for (int i = tid; i < 1584; i += 256) {
        int r = i / 528;
        int rem = i - r * 528;
        int c = rem >> 3;
        int cig = rem & 7;
        int hh = h + r - 1;
        int gc = c - 1;
        bf16x8 val;
#pragma unroll
        for (int j = 0; j < 8; ++j) val[j] = (__bf16)0.f;
        if ((unsigned)hh < 64u && (unsigned)gc < 64u)
            val = xs[(hh * 64 + gc) * 8 + cig];
        *(bf16x8*)&xt[(r * 66 + c) * 64 + ((cig ^ (c & 7)) * 8)] = val;
    }
    const bf16x8* wsrc = (const bf16x8*)Wt2 + (size_t)co0 * 72;
    for (int i = tid; i < 2304; i += 256) {
        int co = i / 72;
        int kc = i - co * 72;
        *(bf16x8*)&wt[co * 576 + ((kc ^ (co & 7)) * 8)] = wsrc[i];
    }
    __syncthreads();

    f32x4 acc0 = {0.f, 0.f, 0.f, 0.f};
    f32x4 acc1 = {0.f, 0.f, 0.f, 0.f};
#pragma unroll
    for (int tap = 0; tap < 9; ++tap) {
        int dh = tap / 3, dw = tap % 3;
#pragma unroll
        for (int ks = 0; ks < 2; ++ks) {
            int cig = ks * 4 + lh;
            int col = nt * 16 + lm + dw;
            bf16x8 bfr = *(const bf16x8*)&xt[(dh * 66 + col) * 64 + ((cig ^ (col & 7)) * 8)];
            int kcg = tap * 8 + cig;
            bf16x8 a0 = *(const bf16x8*)&wt[lm * 576 + ((kcg ^ (lm & 7)) * 8)];
            bf16x8 a1 = *(const bf16x8*)&wt[(16 + lm) * 576 + ((kcg ^ (lm & 7)) * 8)];
            acc0 = __builtin_amdgcn_mfma_f32_16x16x32_bf16(a0, bfr, acc0, 0, 0, 0);
            acc1 = __builtin_amdgcn_mfma_f32_16x16x32_bf16(a1, bfr, acc1, 0, 0, 0);
        }
    }

    size_t obase = (size_t)b * CO_ * NPIX + h * 64 + nt * 16 + lm;
#pragma unroll
    for (int r = 0; r < 4; ++r) {
        int cl0 = lh * 4 + r;
        float y0 = fmaxf(acc0[r] * scs[cl0] + shs[cl0], 0.f);
        local_bf[obase + (size_t)(co0 + cl0) * NPIX] = (__bf16)y0;
        int cl1 = 16 + cl0;
        float y1 = fmaxf(acc1[r] * scs[cl1] + shs[cl1], 0.f);
        local_bf[obase + (size_t)(co0 + cl1) * NPIX] = (__bf16)y1;
    }
}

// two-pass split-KV MFMA flash attention: QT=32, per-half global max first,
// then stream exp+PV with only 2 barriers per tile.
__global__ __launch_bounds__(256) void z_attn9(
    const __bf16* __restrict__ qT, const __bf16* __restrict__ kT, const __bf16* __restrict__ V2,
    __bf16* __restrict__ o_part, float2* __restrict__ ml)
{
    __shared__ __align__(16) unsigned char smem[16896];
    __shared__ float wredA[4][16], wredB[4][16];
    __bf16* pA = (__bf16*)smem;
    __bf16* pB = (__bf16*)(smem + 8448);
    float* o_lds = (float*)smem;

    int tid = threadIdx.x;
    int b = blockIdx.x >> 8;
    int half = (blockIdx.x >> 7) & 1;
    int q0 = (blockIdx.x & 127) * 32;
    int l = tid & 63;
    int w = tid >> 6;
    int lm = l & 15;
    int g = l >> 4;

    bf16x8 qfA, qfB;
#pragma unroll
    for (int j = 0; j < 8; ++j) { qfA[j] = (__bf16)0.f; qfB[j] = (__bf16)0.f; }
    const __bf16* qtb = qT + (size_t)b * NPIX * CQ_;
    if (g < 2) {
        qfA = *(const bf16x8*)&qtb[(size_t)(q0 + lm) * CQ_ + g * 8];
        qfB = *(const bf16x8*)&qtb[(size_t)(q0 + 16 + lm) * CQ_ + g * 8];
    }

    const bf16x8* vbase = (const bf16x8*)V2 + (size_t)b * 65536;
    const __bf16* ktb = kT + (size_t)b * NPIX * CQ_;

    // ---- pass 1: per-half row max (no barriers in loop) ----
    float mxA = -1e30f, mxB = -1e30f;
    for (int t = 0; t < 8; ++t) {
        int m0 = half * 2048 + t * 256;
#pragma unroll
        for (int ms = 0; ms < 4; ++ms) {
            bf16x8 kf;
#pragma unroll
            for (int j = 0; j < 8; ++j) kf[j] = (__bf16)0.f;
            if (g < 2)
                kf = *(const bf16x8*)&ktb[(size_t)(m0 + w * 64 + ms * 16 + lm) * CQ_ + g * 8];
            f32x4 zz = {0.f, 0.f, 0.f, 0.f};
            f32x4 sA = __builtin_amdgcn_mfma_f32_16x16x32_bf16(kf, qfA, zz, 0, 0, 0);
            f32x4 sB = __builtin_amdgcn_mfma_f32_16x16x32_bf16(kf, qfB, zz, 0, 0, 0);
#pragma unroll
            for (int r = 0; r < 4; ++r) {
                mxA = fmaxf(mxA, sA[r]);
                mxB = fmaxf(mxB, sB[r]);
            }
        }
    }
    mxA = fmaxf(mxA, __shfl_xor(mxA, 16));
    mxA = fmaxf(mxA, __shfl_xor(mxA, 32));
    mxB = fmaxf(mxB, __shfl_xor(mxB, 16));
    mxB = fmaxf(mxB, __shfl_xor(mxB, 32));
    if (g == 0) { wredA[w][lm] = mxA; wredB[w][lm] = mxB; }
    __syncthreads();
    float MA = fmaxf(fmaxf(wredA[0][lm], wredA[1][lm]), fmaxf(wredA[2][lm], wredA[3][lm]));
    float MB = fmaxf(fmaxf(wredB[0][lm], wredB[1][lm]), fmaxf(wredB[2][lm], wredB[3][lm]));

    // ---- pass 2: exp + PV, 2 barriers per tile ----
    f32x4 aA0 = {0.f,0.f,0.f,0.f}, aA1 = {0.f,0.f,0.f,0.f};
    f32x4 aB0 = {0.f,0.f,0.f,0.f}, aB1 = {0.f,0.f,0.f,0.f};
    float sumA = 0.f, sumB = 0.f;
    int c0 = w * 32 + lm;
    int c1 = c0 + 16;

    for (int t = 0; t < 8; ++t) {
        int m0 = half * 2048 + t * 256;
#pragma unroll
        for (int ms = 0; ms < 4; ++ms) {
            bf16x8 kf;
#pragma unroll
            for (int j = 0; j < 8; ++j) kf[j] = (__bf16)0.f;
            if (g < 2)
                kf = *(const bf16x8*)&ktb[(size_t)(m0 + w * 64 + ms * 16 + lm) * CQ_ + g * 8];
            f32x4 zz = {0.f, 0.f, 0.f, 0.f};
            f32x4 sA = __builtin_amdgcn_mfma_f32_16x16x32_bf16(kf, qfA, zz, 0, 0, 0);
            f32x4 sB = __builtin_amdgcn_mfma_f32_16x16x32_bf16(kf, qfB, zz, 0, 0, 0);
            float a0 = __expf(sA[0] - MA), a1 = __expf(sA[1] - MA);
            float a2 = __expf(sA[2] - MA), a3 = __expf(sA[3] - MA);
            sumA += (a0 + a1) + (a2 + a3);
            bf16x4 pkA;
            pkA[0] = (__bf16)a0; pkA[1] = (__bf16)a1; pkA[2] = (__bf16)a2; pkA[3] = (__bf16)a3;
            *(bf16x4*)&pA[lm * 264 + w * 64 + ms * 16 + g * 4] = pkA;
            float b0 = __expf(sB[0] - MB), b1 = __expf(sB[1] - MB);
            float b2 = __expf(sB[2] - MB), b3 = __expf(sB[3] - MB);
            sumB += (b0 + b1) + (b2 + b3);
            bf16x4 pkB;
            pkB[0] = (__bf16)b0; pkB[1] = (__bf16)b1; pkB[2] = (__bf16)b2; pkB[3] = (__bf16)b3;
            *(bf16x4*)&pB[lm * 264 + w * 64 + ms * 16 + g * 4] = pkB;
        }
        __syncthreads();
#pragma unroll
        for (int ks = 0; ks < 8; ++ks) {
            int msv = (m0 >> 3) + ks * 4 + g;
            bf16x8 bf0 = vbase[msv * 128 + c0];
            bf16x8 bf1 = vbase[msv * 128 + c1];
            bf16x8 afA = *(const bf16x8*)&pA[lm * 264 + ks * 32 + g * 8];
            bf16x8 afB = *(const bf16x8*)&pB[lm * 264 + ks * 32 + g * 8];
            aA0 = __builtin_amdgcn_mfma_f32_16x16x32_bf16(afA, bf0, aA0, 0, 0, 0);
            aA1 = __builtin_amdgcn_mfma_f32_16x16x32_bf16(afA, bf1, aA1, 0, 0, 0);
            aB0 = __builtin_amdgcn_mfma_f32_16x16x32_bf16(afB, bf0, aB0, 0, 0, 0);
            aB1 = __builtin_amdgcn_mfma_f32_16x16x32_bf16(afB, bf1, aB1, 0, 0, 0);
        }
        __syncthreads();
    }

    // ---- final sums ----
    sumA += __shfl_xor(sumA, 16);
    sumA += __shfl_xor(sumA, 32);
    sumB += __shfl_xor(sumB, 16);
    sumB += __shfl_xor(sumB, 32);
    if (g == 0) { wredA[w][lm] = sumA; wredB[w][lm] = sumB; }
    __syncthreads();
    float lA = (wredA[0][lm] + wredA[1][lm]) + (wredA[2][lm] + wredA[3][lm]);
    float lB = (wredB[0][lm] + wredB[1][lm]) + (wredB[2][lm] + wredB[3][lm]);

    // ---- epilogue: q-tile A then B ----
#pragma unroll
    for (int r = 0; r < 4; ++r) {
        int qrow = g * 4 + r;
        o_lds[c0 * 17 + qrow] = aA0[r];
        o_lds[c1 * 17 + qrow] = aA1[r];
    }
    if (w == 0 && g == 0)
        ml[(size_t)(half * 4 + b) * NPIX + q0 + lm] = make_float2(MA, lA);
    __syncthreads();
    {
        int qi = tid & 15;
        float inv = 1.f / lA;
#pragma unroll
        for (int j = 0; j < 8; ++j) {
            int cc = (tid >> 4) + 16 * j;
            size_t idx = ((size_t)(half * 4 + b) * CO_ + cc) * NPIX + q0 + qi;
            o_part[idx] = (__bf16)(o_lds[cc * 17 + qi] * inv);
        }
    }
    __syncthreads();
#pragma unroll
    for (int r = 0; r < 4; ++r) {
        int qrow = g * 4 + r;
        o_lds[c0 * 17 + qrow] = aB0[r];
        o_lds[c1 * 17 + qrow] = aB1[r];
    }
    if (w == 0 && g == 0)
        ml[(size_t)(half * 4 + b) * NPIX + q0 + 16 + lm] = make_float2(MB, lB);
    __syncthreads();
    {
        int qi = tid & 15;
        float inv = 1.f / lB;
#pragma unroll
        for (int j = 0; j < 8; ++j) {
            int cc = (tid >> 4) + 16 * j;
            size_t idx = ((size_t)(half * 4 + b) * CO_ + cc) * NPIX + q0 + 16 + qi;
            o_part[idx] = (__bf16)(o_lds[cc * 17 + qi] * inv);
        }
    }
}

// fused merge + gate + final (validated r19)
__global__ __launch_bounds__(256) void z_fuseout3(
    const __bf16* __restrict__ local_bf, const __bf16* __restrict__ o_part,
    const float2* __restrict__ ml, const float* __restrict__ a,
    const float* __restrict__ gamp, const __bf16* __restrict__ xT,
    const __bf16* __restrict__ Wb,
    const float* __restrict__ bg, const float* __restrict__ g3, const float* __restrict__ b3n,
    const float* __restrict__ m3, const float* __restrict__ v3,
    const float* __restrict__ bfb, const float* __restrict__ g4, const float* __restrict__ b4,
    const float* __restrict__ m4, const float* __restrict__ v4,
    const float* __restrict__ rsp, float* __restrict__ out)
{
    __shared__ __align__(16) unsigned char smem[32768 + 4096];
    __shared__ float wA[32], wB[32];
    __bf16* sb2 = (__bf16*)smem;
    __bf16* sxT = (__bf16*)(smem + 28672);

    int tid = threadIdx.x;
    int b = blockIdx.x >> 7;
    int n0 = (blockIdx.x & 127) * 32;

    if (tid < 32) {
        float2 m1 = ml[(size_t)b * NPIX + n0 + tid];
        float2 m2 = ml[(size_t)(4 + b) * NPIX + n0 + tid];
        float mm = fmaxf(m1.x, m2.x);
        float w1 = m1.y * __expf(m1.x - mm);
        float w2 = m2.y * __expf(m2.x - mm);
        float inv = 1.f / (w1 + w2);
        wA[tid] = w1 * inv;
        wB[tid] = w2 * inv;
    }
    __syncthreads();

    float gam = gamp[0];
#pragma unroll
    for (int p = 0; p < 4; ++p) {
        int idx = p * 256 + tid;
        int c = idx >> 3, j = idx & 7;
        bf16x4 lv = *(const bf16x4*)&local_bf[((size_t)b * CO_ + c) * NPIX + n0 + j * 4];
        bf16x4 o1 = *(const bf16x4*)&o_part[((size_t)b * CO_ + c) * NPIX + n0 + j * 4];
        bf16x4 o2 = *(const bf16x4*)&o_part[((size_t)(4 + b) * CO_ + c) * NPIX + n0 + j * 4];
        float av[4];
        *(float4*)av = *(const float4*)(a + ((size_t)b * CO_ + c) * NPIX + n0 + j * 4);
#pragma unroll
        for (int e = 0; e < 4; ++e) {
            int n = j * 4 + e;
            int k1 = 128 + c, k2 = 256 + c;
            sb2[n * 448 + (((k1 >> 3) ^ (n & 7)) << 3) + (k1 & 7)] = lv[e];
            float o = (float)o1[e] * wA[n] + (float)o2[e] * wB[n];
            sb2[n * 448 + (((k2 >> 3) ^ (n & 7)) << 3) + (k2 & 7)] = (__bf16)(gam * o + av[e]);
        }
    }
#pragma unroll
    for (int p = 0; p < 2; ++p) {
        int idx = p * 256 + tid;
        int n = idx >> 3, cig = idx & 7;
        bf16x8 vv = ((const bf16x8*)xT)[((size_t)b * NPIX + n0 + n) * 8 + cig];
        *(bf16x8*)&sxT[n * 64 + ((cig ^ (n & 7)) << 3)] = vv;
    }
    __syncthreads();

    int l = tid & 63, w = tid >> 6;
    int lm = l & 15, g = l >> 4;
    int co0 = w * 32;
    int t7 = lm & 7;

    f32x4 p1[2][2];
#pragma unroll
    for (int cs = 0; cs < 2; ++cs) {
        float bv = bg[co0 + cs * 16 + lm];
#pragma unroll
        for (int ns = 0; ns < 2; ++ns) {
            p1[ns][cs][0] = bv; p1[ns][cs][1] = bv; p1[ns][cs][2] = bv; p1[ns][cs][3] = bv;
        }
    }
    const __bf16* Wg2 = Wb;
#pragma unroll
    for (int kc = 0; kc < 8; ++kc) {
        int ch = (16 + kc * 4 + g) ^ t7;
        bf16x8 a0 = *(const bf16x8*)&sb2[lm * 448 + ch * 8];
        bf16x8 a1 = *(const bf16x8*)&sb2[(16 + lm) * 448 + ch * 8];
        bf16x8 b0 = *(const bf16x8*)&Wg2[(size_t)(co0 + lm) * 256 + kc * 32 + g * 8];
        bf16x8 b1 = *(const bf16x8*)&Wg2[(size_t)(co0 + 16 + lm) * 256 + kc * 32 + g * 8];
        p1[0][0] = __builtin_amdgcn_mfma_f32_16x16x32_bf16(a0, b0, p1[0][0], 0, 0, 0);
        p1[0][1] = __builtin_amdgcn_mfma_f32_16x16x32_bf16(a0, b1, p1[0][1], 0, 0, 0);
        p1[1][0] = __builtin_amdgcn_mfma_f32_16x16x32_bf16(a1, b0, p1[1][0], 0, 0, 0);
        p1[1][1] = __builtin_amdgcn_mfma_f32_16x16x32_bf16(a1, b1, p1[1][1], 0, 0, 0);
    }
#pragma unroll
    for (int cs = 0; cs < 2; ++cs) {
        int co = co0 + cs * 16 + lm;
        float sc3 = rsqrtf(v3[co] + EPS_) * g3[co];
        float sh3 = b3n[co] - m3[co] * sc3;
        int kl = 128 + co, ka = 256 + co;
#pragma unroll
        for (int ns = 0; ns < 2; ++ns)
#pragma unroll
            for (int r = 0; r < 4; ++r) {
                int n = ns * 16 + g * 4 + r;
                float z = p1[ns][cs][r] * sc3 + sh3;
                float gate = 1.f / (1.f + __expf(-z));
                float lv = (float)sb2[n * 448 + (((kl >> 3) ^ (n & 7)) << 3) + (kl & 7)];
                float av = (float)sb2[n * 448 + (((ka >> 3) ^ (n & 7)) << 3) + (ka & 7)];
                float fu = gate * lv + (1.f - gate) * av;
                sb2[n * 448 + (((co >> 3) ^ (n & 7)) << 3) + (co & 7)] = (__bf16)fu;
            }
    }
    __syncthreads();

    f32x4 p2[2][2], pr[2][2];
#pragma unroll
    for (int cs = 0; cs < 2; ++cs) {
        float bv = bfb[co0 + cs * 16 + lm];
#pragma unroll
        for (int ns = 0; ns < 2; ++ns) {
            p2[ns][cs][0] = bv; p2[ns][cs][1] = bv; p2[ns][cs][2] = bv; p2[ns][cs][3] = bv;
            pr[ns][cs] = (f32x4){0.f, 0.f, 0.f, 0.f};
        }
    }
    const __bf16* Wf2 = Wb + 32768;
    const __bf16* Wr2 = Wb + 81920;
#pragma unroll
    for (int kc = 0; kc < 12; ++kc) {
        int ch = (kc * 4 + g) ^ t7;
        bf16x8 a0 = *(const bf16x8*)&sb2[lm * 448 + ch * 8];
        bf16x8 a1 = *(const bf16x8*)&sb2[(16 + lm) * 448 + ch * 8];
        bf16x8 b0 = *(const bf16x8*)&Wf2[(size_t)(co0 + lm) * 384 + kc * 32 + g * 8];
        bf16x8 b1 = *(const bf16x8*)&Wf2[(size_t)(co0 + 16 + lm) * 384 + kc * 32 + g * 8];
        p2[0][0] = __builtin_amdgcn_mfma_f32_16x16x32_bf16(a0, b0, p2[0][0], 0, 0, 0);
        p2[0][1] = __builtin_amdgcn_mfma_f32_16x16x32_bf16(a0, b1, p2[0][1], 0, 0, 0);
        p2[1][0] = __builtin_amdgcn_mfma_f32_16x16x32_bf16(a1, b0, p2[1][0], 0, 0, 0);
        p2[1][1] = __builtin_amdgcn_mfma_f32_16x16x32_bf16(a1, b1, p2[1][1], 0, 0, 0);
    }
#pragma unroll
    for (int kc = 0; kc < 2; ++kc) {
        int ch = (kc * 4 + g) ^ t7;
        bf16x8 a0 = *(const bf16x8*)&sxT[lm * 64 + ch * 8];
        bf16x8 a1 = *(const bf16x8*)&sxT[(16 + lm) * 64 + ch * 8];
        bf16x8 b0 = *(const bf16x8*)&Wr2[(size_t)(co0 + lm) * 64 + kc * 32 + g * 8];
        bf16x8 b1 = *(const bf16x8*)&Wr2[(size_t)(co0 + 16 + lm) * 64 + kc * 32 + g * 8];
        pr[0][0] = __builtin_amdgcn_mfma_f32_16x16x32_bf16(a0, b0, pr[0][0], 0, 0, 0);
        pr[0][1] = __builtin_amdgcn_mfma_f32_16x16x32_bf16(a0, b1, pr[0][1], 0, 0, 0);
        pr[1][0] = __builtin_amdgcn_mfma_f32_16x16x32_bf16(a1, b0, pr[1][0], 0, 0, 0);
        pr[1][1] = __builtin_amdgcn_mfma_f32_16x16x32_bf16(a1, b1, pr[1][1], 0, 0, 0);
    }
    __syncthreads();

    float* o_lds = (float*)smem;
    float rsv = rsp[0];
#pragma unroll
    for (int cs = 0; cs < 2; ++cs) {
        int co = co0 + cs * 16 + lm;
        float sc4 = rsqrtf(v4[co] + EPS_) * g4[co];
        float sh4 = b4[co] - m4[co] * sc4;
#pragma unroll
        for (int ns = 0; ns < 2; ++ns)
#pragma unroll
            for (int r = 0; r < 4; ++r) {
                int n = ns * 16 + g * 4 + r;
                float o = fmaxf(p2[ns][cs][r] * sc4 + sh4, 0.f) + rsv * pr[ns][cs][r];
                o_lds[co * 36 + n] = o;
            }
    }
    __syncthreads();
    {
        int c = tid >> 1, h = tid & 1;
#pragma unroll
        for (int j2 = 0; j2 < 4; ++j2) {
            float4 vv = *(float4*)&o_lds[c * 36 + h * 16 + j2 * 4];
            *(float4*)(out + ((size_t)b * CO_ + c) * NPIX + n0 + h * 16 + j2 * 4) = vv;
        }
    }
}

extern "C" void kernel_launch(void* const* d_in, const int* in_sizes, int n_in,
                              void* d_out, int out_size, void* d_ws, size_t ws_size,
                              hipStream_t stream) {
    const float* x   = (const float*)d_in[0];
    const float* W3  = (const float*)d_in[1];
    const float* b3  = (const float*)d_in[2];
    const float* g1  = (const float*)d_in[3];
    const float* b1  = (const float*)d_in[4];
    const float* m1  = (const float*)d_in[5];
    const float* v1  = (const float*)d_in[6];
    const float* Wa  = (const float*)d_in[7];
    const float* ba  = (const float*)d_in[8];
    const float* g2  = (const float*)d_in[9];
    const float* b2  = (const float*)d_in[10];
    const float* m2  = (const float*)d_in[11];
    const float* v2  = (const float*)d_in[12];
    const float* Wq  = (const float*)d_in[13];
    const float* bq  = (const float*)d_in[14];
    const float* Wk  = (const float*)d_in[15];
    const float* bk  = (const float*)d_in[16];
    const float* Wv  = (const float*)d_in[17];
    const float* bv  = (const float*)d_in[18];
    const float* gam = (const float*)d_in[19];
    const float* Wg  = (const float*)d_in[20];
    const float* bg  = (const float*)d_in[21];
    const float* g3  = (const float*)d_in[22];
    const float* b3n = (const float*)d_in[23];
    const float* m3  = (const float*)d_in[24];
    const float* v3  = (const float*)d_in[25];
    const float* Wf  = (const float*)d_in[26];
    const float* bfb = (const float*)d_in[27];
    const float* g4  = (const float*)d_in[28];
    const float* b4  = (const float*)d_in[29];
    const float* m4  = (const float*)d_in[30];
    const float* v4  = (const float*)d_in[31];
    const float* Wr  = (const float*)d_in[32];
    const float* rs  = (const float*)d_in[33];

    float* ws      = (float*)d_ws;
    float* a_      = ws;                         // 8 MB fp32
    __bf16* local_bf = (__bf16*)(ws + 2097152);  // 4 MB bf16
    __bf16* V2     = (__bf16*)(ws + 3145728);    // 4 MB bf16
    __bf16* qT     = (__bf16*)(ws + 4194304);    // 512 KB bf16
    __bf16* kT     = (__bf16*)(ws + 4325376);    // 512 KB bf16
    __bf16* xT     = (__bf16*)(ws + 4456448);    // 2 MB bf16
    __bf16* Wt2    = (__bf16*)(ws + 4980736);    // 147 KB bf16
    __bf16* Wb     = (__bf16*)(ws + 5017600);    // 232 KB bf16
    __bf16* o_part = (__bf16*)(ws + 5076992);    // 8 MB bf16
    float2* ml     = (float2*)(ws + 7174144);    // 256 KB
    // total ≈ 27.9 MB

    float* out = (float*)d_out;

    z_prepx<<<256, 256, 0, stream>>>(x, xT);
    z_prepw2<<<464, 256, 0, stream>>>(W3, Wt2, Wg, Wf, Wr, Wa, Wq, Wk, Wv, Wb);
    z_mega<<<1024, 256, 0, stream>>>(xT, Wb, ba, g2, b2, m2, v2, bq, bk, bv, a_, qT, kT, V2);
    z_attn9<<<1024, 256, 0, stream>>>(qT, kT, V2, o_part, ml);
    z_conv3mb<<<1024, 256, 0, stream>>>(xT, Wt2, b3, g1, b1, m1, v1, local_bf);
    z_fuseout3<<<512, 256, 0, stream>>>(local_bf, o_part, ml, a_, gam, xT, Wb,
                                        bg, g3, b3n, m3, v3, bfb, g4, b4, m4, v4, rs, out);
}